// Round 3
// baseline (7163.746 us; speedup 1.0000x reference)
//
#include <hip/hip_runtime.h>
#include <cstdint>
#include <cstddef>
#include <cmath>

#define NN   100000   // nodes per graph
#define NE   1600000  // edges per graph
#define DD   64       // feature dim
#define NG   4        // graphs
#define NB_  32       // batch
#define NL   50       // candidate list length
#define NCL  2        // attention layers per stack
#define SCAN_NB 49    // ceil(NN/2048)
#define CFB  1568     // conv blocks per graph (64 nodes each, 1568*64 >= NN, multiple of 8)

// ---------------------------------------------------------------- CSR build
__global__ __launch_bounds__(256) void k_hist(const int* __restrict__ dst,
                                              int* __restrict__ cnt, int g0) {
    const int gy = blockIdx.y;
    const int4* d = (const int4*)(dst + (size_t)(g0 + gy) * NE);
    int* c = cnt + (size_t)gy * (NN + 1);
    int q = blockIdx.x * 256 + threadIdx.x;
    if (q < NE / 4) {
        int4 v = d[q];
        atomicAdd(&c[v.x], 1); atomicAdd(&c[v.y], 1);
        atomicAdd(&c[v.z], 1); atomicAdd(&c[v.w], 1);
    }
}

__global__ __launch_bounds__(256) void k_scan1(const int* __restrict__ cnt,
                                               int* __restrict__ part) {
    const int gy = blockIdx.y;
    const int* c = cnt + (size_t)gy * (NN + 1);
    __shared__ int sh[256];
    const int tid = threadIdx.x;
    int base = blockIdx.x * 2048 + tid * 8;
    int s = 0;
    for (int i = 0; i < 8; ++i) { int idx = base + i; if (idx < NN) s += c[idx]; }
    sh[tid] = s; __syncthreads();
    for (int off = 128; off > 0; off >>= 1) {
        if (tid < off) sh[tid] += sh[tid + off];
        __syncthreads();
    }
    if (tid == 0) part[gy * 64 + blockIdx.x] = sh[0];
}

__global__ __launch_bounds__(64) void k_scan2(int* __restrict__ part,
                                              int* __restrict__ row_off) {
    const int gy = blockIdx.y;
    if (threadIdx.x == 0) {
        int* p = part + gy * 64;
        int run = 0;
        for (int i = 0; i < SCAN_NB; ++i) { int t = p[i]; p[i] = run; run += t; }
        row_off[(size_t)gy * (NN + 1) + NN] = run;  // == NE
    }
}

__global__ __launch_bounds__(256) void k_scan3(const int* __restrict__ cnt,
                                               const int* __restrict__ part,
                                               int* __restrict__ row_off,
                                               int* __restrict__ cursor) {
    const int gy = blockIdx.y;
    const int* c = cnt + (size_t)gy * (NN + 1);
    int* ro = row_off + (size_t)gy * (NN + 1);
    int* cu = cursor + (size_t)gy * NN;
    __shared__ int sh[256];
    const int tid = threadIdx.x;
    int base = blockIdx.x * 2048 + tid * 8;
    int vals[8];
    int s = 0;
    for (int i = 0; i < 8; ++i) {
        int idx = base + i;
        int v = (idx < NN) ? c[idx] : 0;
        vals[i] = v; s += v;
    }
    sh[tid] = s; __syncthreads();
    for (int off = 1; off < 256; off <<= 1) {
        int t = (tid >= off) ? sh[tid - off] : 0;
        __syncthreads();
        sh[tid] += t;
        __syncthreads();
    }
    int excl = sh[tid] - s;
    int run = part[gy * 64 + blockIdx.x] + excl;
    for (int i = 0; i < 8; ++i) {
        int idx = base + i;
        if (idx < NN) { ro[idx] = run; cu[idx] = run; run += vals[i]; }
    }
}

// scatter: one packed 8B record per edge (src, ew-bits); 4 edges per thread
__global__ __launch_bounds__(256) void k_scatter(const int* __restrict__ src,
                                                 const int* __restrict__ dst,
                                                 const float* __restrict__ ew,
                                                 int* __restrict__ cursor,
                                                 int2* __restrict__ ed, int g0) {
    const int gy = blockIdx.y;
    const int g = g0 + gy;
    int q = blockIdx.x * 256 + threadIdx.x;
    if (q < NE / 4) {
        int4   dv = ((const int4*)(dst + (size_t)g * NE))[q];
        int4   sv = ((const int4*)(src + (size_t)g * NE))[q];
        float4 wv = ((const float4*)(ew + (size_t)g * NE))[q];
        int* cu = cursor + (size_t)gy * NN;
        int2* eg = ed + (size_t)gy * NE;
        int p0 = atomicAdd(&cu[dv.x], 1); eg[p0] = make_int2(sv.x, __float_as_int(wv.x));
        int p1 = atomicAdd(&cu[dv.y], 1); eg[p1] = make_int2(sv.y, __float_as_int(wv.y));
        int p2 = atomicAdd(&cu[dv.z], 1); eg[p2] = make_int2(sv.z, __float_as_int(wv.z));
        int p3 = atomicAdd(&cu[dv.w], 1); eg[p3] = make_int2(sv.w, __float_as_int(wv.w));
    }
}

// ---------------------------------------------------------------- fused SAGE conv (all nodes, layer 1, relu)
// 8 nodes per wave batch: prefetched edge records, 32-wide gather bursts,
// self/neigh staged in wave-private LDS, weights streamed once per 8 nodes.
// 1D grid with XCD-pair-per-graph swizzle for L2 locality.
__global__ __launch_bounds__(256) void k_conv_full(
    const float* __restrict__ emb, const int* __restrict__ row_off,
    const int2* __restrict__ edges,
    const float* __restrict__ Wsf, const float* __restrict__ Wng,
    const float* __restrict__ bias, float* __restrict__ outh, int g0, int ngr)
{
    int blk = blockIdx.x;
    int gy, bx;
    if (ngr == 4) { gy = (blk >> 1) & 3; bx = ((blk >> 3) << 1) | (blk & 1); }
    else          { gy = 0;              bx = blk; }
    const int chunk = bx * 64;
    if (chunk >= NN) return;
    const int g = g0 + gy;
    const float* feat = emb + (size_t)g * NN * DD;
    const int* ro = row_off + (size_t)gy * (NN + 1);
    const int2* ed = edges + (size_t)gy * NE;
    float* og = outh + (size_t)gy * NN * DD;
    const int lane = threadIdx.x & 63;
    const int wid  = threadIdx.x >> 6;

    __shared__ int lro[65];
    __shared__ __attribute__((aligned(16))) float fs[4][8][DD];
    __shared__ __attribute__((aligned(16))) float ns[4][8][DD];

    {
        int t = threadIdx.x;
        if (t < 65) lro[t] = ro[min(chunk + t, NN)];  // idx>NN clamps -> cnt 0
    }
    __syncthreads();

    const float bv = bias[(size_t)g * DD + lane];
    const float* wsp = Wsf + (size_t)g * DD * DD + (size_t)lane * DD;
    const float* wnp = Wng + (size_t)g * DD * DD + (size_t)lane * DD;

    for (int pass = 0; pass < 2; ++pass) {
        const int lo = wid * 16 + pass * 8;
        const int n0 = chunk + lo;
        // self rows -> LDS (8 independent loads up front)
#pragma unroll
        for (int i = 0; i < 8; ++i) {
            float v = 0.f;
            if (n0 + i < NN) v = feat[(size_t)(n0 + i) * DD + lane];
            fs[wid][i][lane] = v;
        }
        // edge records for all 8 nodes (independent, in flight together)
        int e0v[8], cv[8], rS[8]; float rW[8];
#pragma unroll
        for (int i = 0; i < 8; ++i) {
            e0v[i] = lro[lo + i];
            cv[i]  = lro[lo + i + 1] - e0v[i];
            int c = min(cv[i], 64);
            rS[i] = 0; rW[i] = 0.f;
            if (lane < c) { int2 r = ed[e0v[i] + lane]; rS[i] = r.x; rW[i] = __int_as_float(r.y); }
        }
        // aggregate each node: 32-wide gather burst (covers deg<=32; tails rare)
#pragma unroll
        for (int i = 0; i < 8; ++i) {
            float acc = 0.f;
            {
                float fv[32];
#pragma unroll
                for (int u = 0; u < 32; ++u) {
                    int s = __shfl(rS[i], u);          // v_readlane -> scalar base
                    fv[u] = feat[(size_t)s * DD + lane];
                }
#pragma unroll
                for (int u = 0; u < 32; ++u) {
                    float w = __shfl(rW[i], u);        // padded lanes give w=0
                    acc = fmaf(fv[u], w, acc);
                }
            }
            if (cv[i] > 32) {
                int lim = min(cv[i], 64);
                for (int u = 32; u < lim; ++u) {
                    int s = __shfl(rS[i], u);
                    float w = __shfl(rW[i], u);
                    acc = fmaf(feat[(size_t)s * DD + lane], w, acc);
                }
                for (int bb = e0v[i] + 64; bb < e0v[i] + cv[i]; bb += 64) {
                    int c = min(e0v[i] + cv[i] - bb, 64);
                    int s2 = 0; float w2 = 0.f;
                    if (lane < c) { int2 r = ed[bb + lane]; s2 = r.x; w2 = __int_as_float(r.y); }
                    for (int u = 0; u < c; ++u) {
                        int s = __shfl(s2, u);
                        float w = __shfl(w2, u);
                        acc = fmaf(feat[(size_t)s * DD + lane], w, acc);
                    }
                }
            }
            ns[wid][i][lane] = acc / fmaxf((float)cv[i], 1.f);
        }
        // matvec for 8 nodes; each weight float4 loaded once per 8 nodes
        float o[8];
#pragma unroll
        for (int i = 0; i < 8; ++i) o[i] = bv;
#pragma unroll
        for (int k4 = 0; k4 < 16; ++k4) {
            float4 ws = *(const float4*)(wsp + 4 * k4);
            float4 wn = *(const float4*)(wnp + 4 * k4);
#pragma unroll
            for (int i = 0; i < 8; ++i) {
                float4 f  = *(const float4*)&fs[wid][i][4 * k4];   // LDS broadcast
                float4 nv = *(const float4*)&ns[wid][i][4 * k4];
                o[i] = fmaf(ws.x, f.x,  o[i]);
                o[i] = fmaf(ws.y, f.y,  o[i]);
                o[i] = fmaf(ws.z, f.z,  o[i]);
                o[i] = fmaf(ws.w, f.w,  o[i]);
                o[i] = fmaf(wn.x, nv.x, o[i]);
                o[i] = fmaf(wn.y, nv.y, o[i]);
                o[i] = fmaf(wn.z, nv.z, o[i]);
                o[i] = fmaf(wn.w, nv.w, o[i]);
            }
        }
#pragma unroll
        for (int i = 0; i < 8; ++i)
            if (n0 + i < NN) og[(size_t)(n0 + i) * DD + lane] = fmaxf(o[i], 0.f);
    }
}

// ---------------------------------------------------------------- fused SAGE conv at candidate nodes only (layer 2)
__global__ __launch_bounds__(256) void k_conv_cand(
    const float* __restrict__ hfeat, const int* __restrict__ row_off,
    const int2* __restrict__ edges,
    const float* __restrict__ Wsf, const float* __restrict__ Wng,
    const float* __restrict__ bias, const int* __restrict__ cand,
    float* __restrict__ sel, int g0)
{
    const int gy = blockIdx.y;
    const int g = g0 + gy;
    const float* feat = hfeat + (size_t)gy * NN * DD;
    const int* ro = row_off + (size_t)gy * (NN + 1);
    const int2* ed = edges + (size_t)gy * NE;
    const int lane = threadIdx.x & 63;
    const int wid = threadIdx.x >> 6;

    __shared__ __attribute__((aligned(16))) float fs[4][DD];
    __shared__ __attribute__((aligned(16))) float nsh[4][DD];

    int t = blockIdx.x * 4 + wid;  // 0..1599
    if (t < NB_ * NL) {
        int b = t / NL;
        int l = t - b * NL;
        int n = cand[((size_t)b * NG + g) * NL + l];
        const int e0 = ro[n], e1 = ro[n + 1];
        const float fself = feat[(size_t)n * DD + lane];
        float acc = 0.f;
        for (int base = e0; base < e1; base += 64) {
            const int cnt = min(e1 - base, 64);
            int   myS = 0;
            float myW = 0.f;
            if (lane < cnt) {
                int2 r = ed[base + lane];
                myS = r.x; myW = __int_as_float(r.y);
            }
            for (int j = 0; j < cnt; j += 16) {
                float fv[16], wv[16];
#pragma unroll
                for (int u = 0; u < 16; ++u) {
                    int s = __shfl(myS, j + u);
                    wv[u] = __shfl(myW, j + u);
                    fv[u] = feat[(size_t)s * DD + lane];
                }
#pragma unroll
                for (int u = 0; u < 16; ++u) acc = fmaf(fv[u], wv[u], acc);
            }
        }
        float neigh = acc / fmaxf((float)(e1 - e0), 1.f);
        fs[wid][lane] = fself;
        nsh[wid][lane] = neigh;
        const float* wsp = Wsf + (size_t)g * DD * DD + (size_t)lane * DD;
        const float* wnp = Wng + (size_t)g * DD * DD + (size_t)lane * DD;
        float o = bias[(size_t)g * DD + lane];
#pragma unroll
        for (int k4 = 0; k4 < 16; ++k4) {
            float4 ws = *(const float4*)(wsp + 4 * k4);
            float4 wn = *(const float4*)(wnp + 4 * k4);
            float4 f = *(const float4*)&fs[wid][4 * k4];
            float4 nv = *(const float4*)&nsh[wid][4 * k4];
            o = fmaf(ws.x, f.x, o);
            o = fmaf(ws.y, f.y, o);
            o = fmaf(ws.z, f.z, o);
            o = fmaf(ws.w, f.w, o);
            o = fmaf(wn.x, nv.x, o);
            o = fmaf(wn.y, nv.y, o);
            o = fmaf(wn.z, nv.z, o);
            o = fmaf(wn.w, nv.w, o);
        }
        sel[(((size_t)b * NG + g) * NL + l) * DD + lane] = o;  // no relu
    }
}

// ---------------------------------------------------------------- attention stack 1: (B*G) blocks over (L=50, D=64)
__global__ __launch_bounds__(256) void k_attn1(
    const float* __restrict__ sel, const float* __restrict__ Q,
    const float* __restrict__ K, const float* __restrict__ V,
    float* __restrict__ xsum)
{
    __shared__ __attribute__((aligned(16))) float x[NL * DD];
    __shared__ __attribute__((aligned(16))) float qp[NL * 68];  // q rows, then P rows (in place)
    __shared__ __attribute__((aligned(16))) float kk[NL * 68];  // k rows, then Y rows
    const int tid = threadIdx.x;
    const int lane = tid & 63;
    const int wid = tid >> 6;
    const int bg = blockIdx.x;
    const float* xin = sel + (size_t)bg * NL * DD;
    for (int i = tid; i < NL * DD; i += 256) x[i] = xin[i];
    __syncthreads();

    for (int layer = 0; layer < NCL; ++layer) {
        const float* Qb = Q + (size_t)layer * DD * DD;
        const float* Kb = K + (size_t)layer * DD * DD;
        const float* Vb = V + (size_t)layer * DD * DD;
        float wrow[DD];
        // q = x @ Q.T
#pragma unroll
        for (int k4 = 0; k4 < 16; ++k4) {
            float4 a = *(const float4*)(Qb + (size_t)lane * DD + 4 * k4);
            wrow[4 * k4 + 0] = a.x; wrow[4 * k4 + 1] = a.y; wrow[4 * k4 + 2] = a.z; wrow[4 * k4 + 3] = a.w;
        }
        for (int l = wid; l < NL; l += 4) {
            float acc = 0.f;
#pragma unroll
            for (int k4 = 0; k4 < 16; ++k4) {
                float4 xv = *(const float4*)&x[l * DD + 4 * k4];
                acc = fmaf(wrow[4 * k4 + 0], xv.x, acc);
                acc = fmaf(wrow[4 * k4 + 1], xv.y, acc);
                acc = fmaf(wrow[4 * k4 + 2], xv.z, acc);
                acc = fmaf(wrow[4 * k4 + 3], xv.w, acc);
            }
            qp[l * 68 + lane] = acc;
        }
        // k = x @ K.T
#pragma unroll
        for (int k4 = 0; k4 < 16; ++k4) {
            float4 a = *(const float4*)(Kb + (size_t)lane * DD + 4 * k4);
            wrow[4 * k4 + 0] = a.x; wrow[4 * k4 + 1] = a.y; wrow[4 * k4 + 2] = a.z; wrow[4 * k4 + 3] = a.w;
        }
        for (int l = wid; l < NL; l += 4) {
            float acc = 0.f;
#pragma unroll
            for (int k4 = 0; k4 < 16; ++k4) {
                float4 xv = *(const float4*)&x[l * DD + 4 * k4];
                acc = fmaf(wrow[4 * k4 + 0], xv.x, acc);
                acc = fmaf(wrow[4 * k4 + 1], xv.y, acc);
                acc = fmaf(wrow[4 * k4 + 2], xv.z, acc);
                acc = fmaf(wrow[4 * k4 + 3], xv.w, acc);
            }
            kk[l * 68 + lane] = acc;
        }
        __syncthreads();
        // scores + softmax; P written into qp row (own wave's rows only)
        for (int l = wid; l < NL; l += 4) {
            float s;
            if (lane < NL) {
                float acc = 0.f;
#pragma unroll
                for (int k4 = 0; k4 < 16; ++k4) {
                    float4 qv = *(const float4*)&qp[l * 68 + 4 * k4];
                    float4 kv = *(const float4*)&kk[lane * 68 + 4 * k4];
                    acc += qv.x * kv.x + qv.y * kv.y + qv.z * kv.z + qv.w * kv.w;
                }
                s = acc * 0.125f;
            } else {
                s = -INFINITY;
            }
            float mx = s;
#pragma unroll
            for (int m = 32; m >= 1; m >>= 1) mx = fmaxf(mx, __shfl_xor(mx, m));
            float pe = __expf(s - mx);  // lanes >= 50 give 0
            float sm = pe;
#pragma unroll
            for (int m = 32; m >= 1; m >>= 1) sm += __shfl_xor(sm, m);
            qp[l * 68 + lane] = pe / sm;
        }
        __syncthreads();
        // Y = P @ X  -> kk
        for (int l = wid; l < NL; l += 4) {
            float acc = 0.f;
            for (int m = 0; m < NL; ++m)
                acc = fmaf(qp[l * 68 + m], x[m * DD + lane], acc);
            kk[l * 68 + lane] = acc;
        }
        __syncthreads();
        // out = Y @ V.T -> x
#pragma unroll
        for (int k4 = 0; k4 < 16; ++k4) {
            float4 a = *(const float4*)(Vb + (size_t)lane * DD + 4 * k4);
            wrow[4 * k4 + 0] = a.x; wrow[4 * k4 + 1] = a.y; wrow[4 * k4 + 2] = a.z; wrow[4 * k4 + 3] = a.w;
        }
        for (int l = wid; l < NL; l += 4) {
            float acc = 0.f;
#pragma unroll
            for (int k4 = 0; k4 < 16; ++k4) {
                float4 yv = *(const float4*)&kk[l * 68 + 4 * k4];
                acc = fmaf(wrow[4 * k4 + 0], yv.x, acc);
                acc = fmaf(wrow[4 * k4 + 1], yv.y, acc);
                acc = fmaf(wrow[4 * k4 + 2], yv.z, acc);
                acc = fmaf(wrow[4 * k4 + 3], yv.w, acc);
            }
            x[l * DD + lane] = acc;
        }
        __syncthreads();
    }
    if (wid == 0) {
        float acc = 0.f;
        for (int l = 0; l < NL; ++l) acc += x[l * DD + lane];
        xsum[(size_t)bg * DD + lane] = acc;
    }
}

// ---------------------------------------------------------------- attention stack 2: B blocks over (G=4, D=64)
__global__ __launch_bounds__(64) void k_attn2(
    const float* __restrict__ xin, const float* __restrict__ Q,
    const float* __restrict__ K, const float* __restrict__ V,
    float* __restrict__ out)
{
    __shared__ __attribute__((aligned(16))) float x[NG * DD];
    const int j = threadIdx.x;
    const int b = blockIdx.x;
    for (int i = j; i < NG * DD; i += 64) x[i] = xin[(size_t)b * NG * DD + i];
    __syncthreads();
    float o[NG];
    for (int layer = 0; layer < NCL; ++layer) {
        float wrow[DD];
        float q4[NG], k4v[NG], v4[NG];
        const float* Qb = Q + (size_t)layer * DD * DD + (size_t)j * DD;
        const float* Kb = K + (size_t)layer * DD * DD + (size_t)j * DD;
        const float* Vb = V + (size_t)layer * DD * DD + (size_t)j * DD;
#pragma unroll
        for (int k4 = 0; k4 < 16; ++k4) {
            float4 a = *(const float4*)(Qb + 4 * k4);
            wrow[4 * k4 + 0] = a.x; wrow[4 * k4 + 1] = a.y; wrow[4 * k4 + 2] = a.z; wrow[4 * k4 + 3] = a.w;
        }
#pragma unroll
        for (int g = 0; g < NG; ++g) {
            float acc = 0.f;
#pragma unroll
            for (int k4 = 0; k4 < 16; ++k4) {
                float4 xv = *(const float4*)&x[g * DD + 4 * k4];
                acc = fmaf(wrow[4 * k4 + 0], xv.x, acc);
                acc = fmaf(wrow[4 * k4 + 1], xv.y, acc);
                acc = fmaf(wrow[4 * k4 + 2], xv.z, acc);
                acc = fmaf(wrow[4 * k4 + 3], xv.w, acc);
            }
            q4[g] = acc;
        }
#pragma unroll
        for (int k4 = 0; k4 < 16; ++k4) {
            float4 a = *(const float4*)(Kb + 4 * k4);
            wrow[4 * k4 + 0] = a.x; wrow[4 * k4 + 1] = a.y; wrow[4 * k4 + 2] = a.z; wrow[4 * k4 + 3] = a.w;
        }
#pragma unroll
        for (int g = 0; g < NG; ++g) {
            float acc = 0.f;
#pragma unroll
            for (int k4 = 0; k4 < 16; ++k4) {
                float4 xv = *(const float4*)&x[g * DD + 4 * k4];
                acc = fmaf(wrow[4 * k4 + 0], xv.x, acc);
                acc = fmaf(wrow[4 * k4 + 1], xv.y, acc);
                acc = fmaf(wrow[4 * k4 + 2], xv.z, acc);
                acc = fmaf(wrow[4 * k4 + 3], xv.w, acc);
            }
            k4v[g] = acc;
        }
#pragma unroll
        for (int k4 = 0; k4 < 16; ++k4) {
            float4 a = *(const float4*)(Vb + 4 * k4);
            wrow[4 * k4 + 0] = a.x; wrow[4 * k4 + 1] = a.y; wrow[4 * k4 + 2] = a.z; wrow[4 * k4 + 3] = a.w;
        }
#pragma unroll
        for (int g = 0; g < NG; ++g) {
            float acc = 0.f;
#pragma unroll
            for (int k4 = 0; k4 < 16; ++k4) {
                float4 xv = *(const float4*)&x[g * DD + 4 * k4];
                acc = fmaf(wrow[4 * k4 + 0], xv.x, acc);
                acc = fmaf(wrow[4 * k4 + 1], xv.y, acc);
                acc = fmaf(wrow[4 * k4 + 2], xv.z, acc);
                acc = fmaf(wrow[4 * k4 + 3], xv.w, acc);
            }
            v4[g] = acc;
        }
        // scores via full-wave reduction over the feature lanes
        float p[NG][NG];
#pragma unroll
        for (int l = 0; l < NG; ++l) {
#pragma unroll
            for (int m = 0; m < NG; ++m) {
                float t = q4[l] * k4v[m];
#pragma unroll
                for (int mk = 32; mk >= 1; mk >>= 1) t += __shfl_xor(t, mk);
                p[l][m] = t * 0.125f;
            }
        }
#pragma unroll
        for (int l = 0; l < NG; ++l) {
            float mx = fmaxf(fmaxf(p[l][0], p[l][1]), fmaxf(p[l][2], p[l][3]));
            float e0 = __expf(p[l][0] - mx), e1 = __expf(p[l][1] - mx);
            float e2 = __expf(p[l][2] - mx), e3 = __expf(p[l][3] - mx);
            float inv = 1.f / (e0 + e1 + e2 + e3);
            o[l] = (e0 * v4[0] + e1 * v4[1] + e2 * v4[2] + e3 * v4[3]) * inv;
        }
        __syncthreads();
#pragma unroll
        for (int l = 0; l < NG; ++l) x[l * DD + j] = o[l];
        __syncthreads();
    }
    out[(size_t)b * DD + j] = o[0] + o[1] + o[2] + o[3];
}

// ---------------------------------------------------------------- host
extern "C" void kernel_launch(void* const* d_in, const int* in_sizes, int n_in,
                              void* d_out, int out_size, void* d_ws, size_t ws_size,
                              hipStream_t stream)
{
    const int*   src  = (const int*)  d_in[0];
    const int*   dst  = (const int*)  d_in[1];
    const float* ew   = (const float*)d_in[2];
    const float* emb  = (const float*)d_in[3];
    const float* Ws1  = (const float*)d_in[4];
    const float* Wn1  = (const float*)d_in[5];
    const float* b1   = (const float*)d_in[6];
    const float* Ws2  = (const float*)d_in[7];
    const float* Wn2  = (const float*)d_in[8];
    const float* b2   = (const float*)d_in[9];
    const float* Q1   = (const float*)d_in[10];
    const float* K1   = (const float*)d_in[11];
    const float* V1   = (const float*)d_in[12];
    const float* Q2   = (const float*)d_in[13];
    const float* K2   = (const float*)d_in[14];
    const float* V2   = (const float*)d_in[15];
    const int*   cand = (const int*)  d_in[16];
    float* out = (float*)d_out;

    auto padded = [](size_t b) { return (b + 255) & ~(size_t)255; };
    auto need = [&](int GG) -> size_t {
        size_t s = 0;
        s += padded((size_t)GG * (NN + 1) * 4);   // cnt
        s += padded((size_t)GG * 64 * 4);         // partials
        s += padded((size_t)GG * (NN + 1) * 4);   // row_off
        s += padded((size_t)GG * NN * 4);         // cursor
        s += padded((size_t)GG * NE * 8);         // packed edges
        s += padded((size_t)GG * NN * DD * 4);    // h
        s += padded((size_t)NB_ * NG * NL * DD * 4); // sel
        s += padded((size_t)NB_ * NG * DD * 4);      // xsum
        return s;
    };
    const int GG = (ws_size >= need(4)) ? 4 : 1;

    char* p = (char*)d_ws;
    auto alloc = [&](size_t b) -> void* { void* r = (void*)p; p += padded(b); return r; };
    int*   cnt  = (int*)  alloc((size_t)GG * (NN + 1) * 4);
    int*   part = (int*)  alloc((size_t)GG * 64 * 4);
    int*   roff = (int*)  alloc((size_t)GG * (NN + 1) * 4);
    int*   cur  = (int*)  alloc((size_t)GG * NN * 4);
    int2*  edg  = (int2*) alloc((size_t)GG * NE * 8);
    float* hb   = (float*)alloc((size_t)GG * NN * DD * 4);
    float* sel  = (float*)alloc((size_t)NB_ * NG * NL * DD * 4);
    float* xsum = (float*)alloc((size_t)NB_ * NG * DD * 4);

    const int QB = (NE / 4 + 255) / 256;  // 4-edge-per-thread blocks
    for (int g0 = 0; g0 < NG; g0 += GG) {
        hipMemsetAsync(cnt, 0, (size_t)GG * (NN + 1) * 4, stream);
        k_hist   <<<dim3(QB, GG), 256, 0, stream>>>(dst, cnt, g0);
        k_scan1  <<<dim3(SCAN_NB, GG), 256, 0, stream>>>(cnt, part);
        k_scan2  <<<dim3(1, GG), 64, 0, stream>>>(part, roff);
        k_scan3  <<<dim3(SCAN_NB, GG), 256, 0, stream>>>(cnt, part, roff, cur);
        k_scatter<<<dim3(QB, GG), 256, 0, stream>>>(src, dst, ew, cur, edg, g0);
        k_conv_full<<<CFB * GG, 256, 0, stream>>>(emb, roff, edg, Ws1, Wn1, b1, hb, g0, GG);
        k_conv_cand<<<dim3((NB_ * NL) / 4, GG), 256, 0, stream>>>(hb, roff, edg, Ws2, Wn2, b2, cand, sel, g0);
    }
    k_attn1<<<NB_ * NG, 256, 0, stream>>>(sel, Q1, K1, V1, xsum);
    k_attn2<<<NB_, 64, 0, stream>>>(xsum, Q2, K2, V2, out);
}

// Round 4
// 973.500 us; speedup vs baseline: 7.3588x; 7.3588x over previous
//
#include <hip/hip_runtime.h>
#include <cstdint>
#include <cstddef>
#include <cmath>

#define NN   100000   // nodes per graph
#define NE   1600000  // edges per graph
#define DD   64       // feature dim
#define NG   4        // graphs
#define NB_  32       // batch
#define NL   50       // candidate list length
#define NCL  2        // attention layers per stack
#define SCAN_NB 49    // ceil(NN/2048)

// ---------------------------------------------------------------- CSR build
__global__ __launch_bounds__(256) void k_hist(const int* __restrict__ dst,
                                              int* __restrict__ cnt, int g0) {
    const int gy = blockIdx.y;
    const int4* d = (const int4*)(dst + (size_t)(g0 + gy) * NE);
    int* c = cnt + (size_t)gy * (NN + 1);
    int q = blockIdx.x * 256 + threadIdx.x;
    if (q < NE / 4) {
        int4 v = d[q];
        atomicAdd(&c[v.x], 1); atomicAdd(&c[v.y], 1);
        atomicAdd(&c[v.z], 1); atomicAdd(&c[v.w], 1);
    }
}

__global__ __launch_bounds__(256) void k_scan1(const int* __restrict__ cnt,
                                               int* __restrict__ part) {
    const int gy = blockIdx.y;
    const int* c = cnt + (size_t)gy * (NN + 1);
    __shared__ int sh[256];
    const int tid = threadIdx.x;
    int base = blockIdx.x * 2048 + tid * 8;
    int s = 0;
    for (int i = 0; i < 8; ++i) { int idx = base + i; if (idx < NN) s += c[idx]; }
    sh[tid] = s; __syncthreads();
    for (int off = 128; off > 0; off >>= 1) {
        if (tid < off) sh[tid] += sh[tid + off];
        __syncthreads();
    }
    if (tid == 0) part[gy * 64 + blockIdx.x] = sh[0];
}

__global__ __launch_bounds__(64) void k_scan2(int* __restrict__ part,
                                              int* __restrict__ row_off) {
    const int gy = blockIdx.y;
    if (threadIdx.x == 0) {
        int* p = part + gy * 64;
        int run = 0;
        for (int i = 0; i < SCAN_NB; ++i) { int t = p[i]; p[i] = run; run += t; }
        row_off[(size_t)gy * (NN + 1) + NN] = run;  // == NE
    }
}

__global__ __launch_bounds__(256) void k_scan3(const int* __restrict__ cnt,
                                               const int* __restrict__ part,
                                               int* __restrict__ row_off,
                                               int* __restrict__ cursor) {
    const int gy = blockIdx.y;
    const int* c = cnt + (size_t)gy * (NN + 1);
    int* ro = row_off + (size_t)gy * (NN + 1);
    int* cu = cursor + (size_t)gy * NN;
    __shared__ int sh[256];
    const int tid = threadIdx.x;
    int base = blockIdx.x * 2048 + tid * 8;
    int vals[8];
    int s = 0;
    for (int i = 0; i < 8; ++i) {
        int idx = base + i;
        int v = (idx < NN) ? c[idx] : 0;
        vals[i] = v; s += v;
    }
    sh[tid] = s; __syncthreads();
    for (int off = 1; off < 256; off <<= 1) {
        int t = (tid >= off) ? sh[tid - off] : 0;
        __syncthreads();
        sh[tid] += t;
        __syncthreads();
    }
    int excl = sh[tid] - s;
    int run = part[gy * 64 + blockIdx.x] + excl;
    for (int i = 0; i < 8; ++i) {
        int idx = base + i;
        if (idx < NN) { ro[idx] = run; cu[idx] = run; run += vals[i]; }
    }
}

// scatter: one packed 8B record per edge (src, ew-bits); 4 edges per thread
__global__ __launch_bounds__(256) void k_scatter(const int* __restrict__ src,
                                                 const int* __restrict__ dst,
                                                 const float* __restrict__ ew,
                                                 int* __restrict__ cursor,
                                                 int2* __restrict__ ed, int g0) {
    const int gy = blockIdx.y;
    const int g = g0 + gy;
    int q = blockIdx.x * 256 + threadIdx.x;
    if (q < NE / 4) {
        int4   dv = ((const int4*)(dst + (size_t)g * NE))[q];
        int4   sv = ((const int4*)(src + (size_t)g * NE))[q];
        float4 wv = ((const float4*)(ew + (size_t)g * NE))[q];
        int* cu = cursor + (size_t)gy * NN;
        int2* eg = ed + (size_t)gy * NE;
        int p0 = atomicAdd(&cu[dv.x], 1); eg[p0] = make_int2(sv.x, __float_as_int(wv.x));
        int p1 = atomicAdd(&cu[dv.y], 1); eg[p1] = make_int2(sv.y, __float_as_int(wv.y));
        int p2 = atomicAdd(&cu[dv.z], 1); eg[p2] = make_int2(sv.z, __float_as_int(wv.z));
        int p3 = atomicAdd(&cu[dv.w], 1); eg[p3] = make_int2(sv.w, __float_as_int(wv.w));
    }
}

// ---------------------------------------------------------------- mark nodes whose h is needed
// (candidates + sources of their in-edges). Wave per candidate.
__global__ __launch_bounds__(256) void k_mark(const int* __restrict__ row_off,
                                              const int2* __restrict__ edges,
                                              const int* __restrict__ cand,
                                              int* __restrict__ mark, int g0) {
    const int gy = blockIdx.y;
    const int g = g0 + gy;
    const int* ro = row_off + (size_t)gy * (NN + 1);
    const int2* ed = edges + (size_t)gy * NE;
    int* mk = mark + (size_t)gy * NN;
    const int lane = threadIdx.x & 63;
    int t = blockIdx.x * 4 + (threadIdx.x >> 6);
    if (t < NB_ * NL) {
        int b = t / NL, l = t - b * NL;
        int n = cand[((size_t)b * NG + g) * NL + l];
        if (lane == 0) mk[n] = 1;
        int e0 = ro[n], e1 = ro[n + 1];
        for (int i = e0 + lane; i < e1; i += 64) mk[ed[i].x] = 1;
    }
}

// compact marked nodes -> list (block sums, offsets, scatter) — same pattern as scan
__global__ __launch_bounds__(256) void k_cscan1(const int* __restrict__ mark,
                                                int* __restrict__ partc) {
    const int gy = blockIdx.y;
    const int* m = mark + (size_t)gy * NN;
    __shared__ int sh[256];
    const int tid = threadIdx.x;
    int base = blockIdx.x * 2048 + tid * 8;
    int s = 0;
    for (int i = 0; i < 8; ++i) { int idx = base + i; if (idx < NN) s += m[idx]; }
    sh[tid] = s; __syncthreads();
    for (int off = 128; off > 0; off >>= 1) {
        if (tid < off) sh[tid] += sh[tid + off];
        __syncthreads();
    }
    if (tid == 0) partc[gy * 64 + blockIdx.x] = sh[0];
}

__global__ __launch_bounds__(64) void k_cscan2(int* __restrict__ partc,
                                               int* __restrict__ nlist) {
    const int gy = blockIdx.y;
    if (threadIdx.x == 0) {
        int* p = partc + gy * 64;
        int run = 0;
        for (int i = 0; i < SCAN_NB; ++i) { int t = p[i]; p[i] = run; run += t; }
        nlist[gy] = run;
    }
}

__global__ __launch_bounds__(256) void k_cscan3(const int* __restrict__ mark,
                                                const int* __restrict__ partc,
                                                int* __restrict__ list) {
    const int gy = blockIdx.y;
    const int* m = mark + (size_t)gy * NN;
    int* li = list + (size_t)gy * NN;
    __shared__ int sh[256];
    const int tid = threadIdx.x;
    int base = blockIdx.x * 2048 + tid * 8;
    int vals[8];
    int s = 0;
    for (int i = 0; i < 8; ++i) {
        int idx = base + i;
        int v = (idx < NN) ? m[idx] : 0;
        vals[i] = v; s += v;
    }
    sh[tid] = s; __syncthreads();
    for (int off = 1; off < 256; off <<= 1) {
        int t = (tid >= off) ? sh[tid - off] : 0;
        __syncthreads();
        sh[tid] += t;
        __syncthreads();
    }
    int excl = sh[tid] - s;
    int run = partc[gy * 64 + blockIdx.x] + excl;
    for (int i = 0; i < 8; ++i) {
        int idx = base + i;
        if (idx < NN && vals[i]) { li[run] = idx; ++run; }
    }
}

// ---------------------------------------------------------------- fused SAGE conv (layer 1, relu) over the marked-node list
// Body identical to the proven round-2 kernel; only the node source is indirected.
__global__ __launch_bounds__(256) void k_conv_full(
    const float* __restrict__ emb, const int* __restrict__ row_off,
    const int2* __restrict__ edges,
    const float* __restrict__ Wsf, const float* __restrict__ Wng,
    const float* __restrict__ bias, float* __restrict__ outh,
    const int* __restrict__ list, const int* __restrict__ nlist, int g0)
{
    const int gy = blockIdx.y;
    const int g = g0 + gy;
    const float* feat = emb + (size_t)g * NN * DD;
    const int* ro = row_off + (size_t)gy * (NN + 1);
    const int2* ed = edges + (size_t)gy * NE;
    const int* li = list + (size_t)gy * NN;
    float* og = outh + (size_t)gy * NN * DD;
    const int lane = threadIdx.x & 63;
    const int wid = threadIdx.x >> 6;

    float wsr[DD], wnr[DD];
    {
        const float* wsp = Wsf + (size_t)g * DD * DD + (size_t)lane * DD;
        const float* wnp = Wng + (size_t)g * DD * DD + (size_t)lane * DD;
#pragma unroll
        for (int k4 = 0; k4 < 16; ++k4) {
            float4 a = *(const float4*)(wsp + 4 * k4);
            wsr[4 * k4 + 0] = a.x; wsr[4 * k4 + 1] = a.y; wsr[4 * k4 + 2] = a.z; wsr[4 * k4 + 3] = a.w;
            float4 c = *(const float4*)(wnp + 4 * k4);
            wnr[4 * k4 + 0] = c.x; wnr[4 * k4 + 1] = c.y; wnr[4 * k4 + 2] = c.z; wnr[4 * k4 + 3] = c.w;
        }
    }
    const float bv = bias[(size_t)g * DD + lane];

    __shared__ __attribute__((aligned(16))) float fs[4][DD];
    __shared__ __attribute__((aligned(16))) float ns[4][DD];

    const int nl = nlist[gy];
    const int wglob = blockIdx.x * 4 + wid;
    const int wstep = gridDim.x * 4;
    for (int t = wglob; t < nl; t += wstep) {
        const int n = li[t];
        const int e0 = ro[n], e1 = ro[n + 1];
        const float fself = feat[(size_t)n * DD + lane];  // issue early
        float acc = 0.f;
        for (int base = e0; base < e1; base += 64) {
            const int cnt = min(e1 - base, 64);
            int   myS = 0;
            float myW = 0.f;
            if (lane < cnt) {
                int2 r = ed[base + lane];
                myS = r.x; myW = __int_as_float(r.y);
            }
            for (int j = 0; j < cnt; j += 8) {
                float fv[8], wv[8];
#pragma unroll
                for (int u = 0; u < 8; ++u) {
                    int s = __shfl(myS, j + u);        // padded lanes give s=0, w=0
                    wv[u] = __shfl(myW, j + u);
                    fv[u] = feat[(size_t)s * DD + lane];
                }
#pragma unroll
                for (int u = 0; u < 8; ++u) acc = fmaf(fv[u], wv[u], acc);
            }
        }
        float neigh = acc / fmaxf((float)(e1 - e0), 1.f);
        fs[wid][lane] = fself;
        ns[wid][lane] = neigh;
        float o = bv;
#pragma unroll
        for (int k4 = 0; k4 < 16; ++k4) {
            float4 f = *(const float4*)&fs[wid][4 * k4];
            float4 nv = *(const float4*)&ns[wid][4 * k4];
            o = fmaf(wsr[4 * k4 + 0], f.x, o);
            o = fmaf(wsr[4 * k4 + 1], f.y, o);
            o = fmaf(wsr[4 * k4 + 2], f.z, o);
            o = fmaf(wsr[4 * k4 + 3], f.w, o);
            o = fmaf(wnr[4 * k4 + 0], nv.x, o);
            o = fmaf(wnr[4 * k4 + 1], nv.y, o);
            o = fmaf(wnr[4 * k4 + 2], nv.z, o);
            o = fmaf(wnr[4 * k4 + 3], nv.w, o);
        }
        o = fmaxf(o, 0.f);  // relu (layer 1)
        og[(size_t)n * DD + lane] = o;
    }
}

// ---------------------------------------------------------------- fused SAGE conv at candidate nodes only (layer 2)
__global__ __launch_bounds__(256) void k_conv_cand(
    const float* __restrict__ hfeat, const int* __restrict__ row_off,
    const int2* __restrict__ edges,
    const float* __restrict__ Wsf, const float* __restrict__ Wng,
    const float* __restrict__ bias, const int* __restrict__ cand,
    float* __restrict__ sel, int g0)
{
    const int gy = blockIdx.y;
    const int g = g0 + gy;
    const float* feat = hfeat + (size_t)gy * NN * DD;
    const int* ro = row_off + (size_t)gy * (NN + 1);
    const int2* ed = edges + (size_t)gy * NE;
    const int lane = threadIdx.x & 63;
    const int wid = threadIdx.x >> 6;

    float wsr[DD], wnr[DD];
    {
        const float* wsp = Wsf + (size_t)g * DD * DD + (size_t)lane * DD;
        const float* wnp = Wng + (size_t)g * DD * DD + (size_t)lane * DD;
#pragma unroll
        for (int k4 = 0; k4 < 16; ++k4) {
            float4 a = *(const float4*)(wsp + 4 * k4);
            wsr[4 * k4 + 0] = a.x; wsr[4 * k4 + 1] = a.y; wsr[4 * k4 + 2] = a.z; wsr[4 * k4 + 3] = a.w;
            float4 c = *(const float4*)(wnp + 4 * k4);
            wnr[4 * k4 + 0] = c.x; wnr[4 * k4 + 1] = c.y; wnr[4 * k4 + 2] = c.z; wnr[4 * k4 + 3] = c.w;
        }
    }
    const float bv = bias[(size_t)g * DD + lane];

    __shared__ __attribute__((aligned(16))) float fs[4][DD];
    __shared__ __attribute__((aligned(16))) float nsh[4][DD];

    int t = blockIdx.x * 4 + wid;  // 0..1599
    if (t < NB_ * NL) {
        int b = t / NL;
        int l = t - b * NL;
        int n = cand[((size_t)b * NG + g) * NL + l];
        const int e0 = ro[n], e1 = ro[n + 1];
        const float fself = feat[(size_t)n * DD + lane];
        float acc = 0.f;
        for (int base = e0; base < e1; base += 64) {
            const int cnt = min(e1 - base, 64);
            int   myS = 0;
            float myW = 0.f;
            if (lane < cnt) {
                int2 r = ed[base + lane];
                myS = r.x; myW = __int_as_float(r.y);
            }
            for (int j = 0; j < cnt; j += 8) {
                float fv[8], wv[8];
#pragma unroll
                for (int u = 0; u < 8; ++u) {
                    int s = __shfl(myS, j + u);
                    wv[u] = __shfl(myW, j + u);
                    fv[u] = feat[(size_t)s * DD + lane];
                }
#pragma unroll
                for (int u = 0; u < 8; ++u) acc = fmaf(fv[u], wv[u], acc);
            }
        }
        float neigh = acc / fmaxf((float)(e1 - e0), 1.f);
        fs[wid][lane] = fself;
        nsh[wid][lane] = neigh;
        float o = bv;
#pragma unroll
        for (int k4 = 0; k4 < 16; ++k4) {
            float4 f = *(const float4*)&fs[wid][4 * k4];
            float4 nv = *(const float4*)&nsh[wid][4 * k4];
            o = fmaf(wsr[4 * k4 + 0], f.x, o);
            o = fmaf(wsr[4 * k4 + 1], f.y, o);
            o = fmaf(wsr[4 * k4 + 2], f.z, o);
            o = fmaf(wsr[4 * k4 + 3], f.w, o);
            o = fmaf(wnr[4 * k4 + 0], nv.x, o);
            o = fmaf(wnr[4 * k4 + 1], nv.y, o);
            o = fmaf(wnr[4 * k4 + 2], nv.z, o);
            o = fmaf(wnr[4 * k4 + 3], nv.w, o);
        }
        sel[(((size_t)b * NG + g) * NL + l) * DD + lane] = o;  // no relu
    }
}

// ---------------------------------------------------------------- attention stack 1: (B*G) blocks over (L=50, D=64)
__global__ __launch_bounds__(256) void k_attn1(
    const float* __restrict__ sel, const float* __restrict__ Q,
    const float* __restrict__ K, const float* __restrict__ V,
    float* __restrict__ xsum)
{
    __shared__ __attribute__((aligned(16))) float x[NL * DD];
    __shared__ __attribute__((aligned(16))) float qp[NL * 68];  // q rows, then P rows (in place)
    __shared__ __attribute__((aligned(16))) float kk[NL * 68];  // k rows, then Y rows
    const int tid = threadIdx.x;
    const int lane = tid & 63;
    const int wid = tid >> 6;
    const int bg = blockIdx.x;
    const float* xin = sel + (size_t)bg * NL * DD;
    for (int i = tid; i < NL * DD; i += 256) x[i] = xin[i];
    __syncthreads();

    for (int layer = 0; layer < NCL; ++layer) {
        const float* Qb = Q + (size_t)layer * DD * DD;
        const float* Kb = K + (size_t)layer * DD * DD;
        const float* Vb = V + (size_t)layer * DD * DD;
        float wrow[DD];
        // q = x @ Q.T
#pragma unroll
        for (int k4 = 0; k4 < 16; ++k4) {
            float4 a = *(const float4*)(Qb + (size_t)lane * DD + 4 * k4);
            wrow[4 * k4 + 0] = a.x; wrow[4 * k4 + 1] = a.y; wrow[4 * k4 + 2] = a.z; wrow[4 * k4 + 3] = a.w;
        }
        for (int l = wid; l < NL; l += 4) {
            float acc = 0.f;
#pragma unroll
            for (int k4 = 0; k4 < 16; ++k4) {
                float4 xv = *(const float4*)&x[l * DD + 4 * k4];
                acc = fmaf(wrow[4 * k4 + 0], xv.x, acc);
                acc = fmaf(wrow[4 * k4 + 1], xv.y, acc);
                acc = fmaf(wrow[4 * k4 + 2], xv.z, acc);
                acc = fmaf(wrow[4 * k4 + 3], xv.w, acc);
            }
            qp[l * 68 + lane] = acc;
        }
        // k = x @ K.T
#pragma unroll
        for (int k4 = 0; k4 < 16; ++k4) {
            float4 a = *(const float4*)(Kb + (size_t)lane * DD + 4 * k4);
            wrow[4 * k4 + 0] = a.x; wrow[4 * k4 + 1] = a.y; wrow[4 * k4 + 2] = a.z; wrow[4 * k4 + 3] = a.w;
        }
        for (int l = wid; l < NL; l += 4) {
            float acc = 0.f;
#pragma unroll
            for (int k4 = 0; k4 < 16; ++k4) {
                float4 xv = *(const float4*)&x[l * DD + 4 * k4];
                acc = fmaf(wrow[4 * k4 + 0], xv.x, acc);
                acc = fmaf(wrow[4 * k4 + 1], xv.y, acc);
                acc = fmaf(wrow[4 * k4 + 2], xv.z, acc);
                acc = fmaf(wrow[4 * k4 + 3], xv.w, acc);
            }
            kk[l * 68 + lane] = acc;
        }
        __syncthreads();
        // scores + softmax; P written into qp row (own wave's rows only)
        for (int l = wid; l < NL; l += 4) {
            float s;
            if (lane < NL) {
                float acc = 0.f;
#pragma unroll
                for (int k4 = 0; k4 < 16; ++k4) {
                    float4 qv = *(const float4*)&qp[l * 68 + 4 * k4];
                    float4 kv = *(const float4*)&kk[lane * 68 + 4 * k4];
                    acc += qv.x * kv.x + qv.y * kv.y + qv.z * kv.z + qv.w * kv.w;
                }
                s = acc * 0.125f;
            } else {
                s = -INFINITY;
            }
            float mx = s;
#pragma unroll
            for (int m = 32; m >= 1; m >>= 1) mx = fmaxf(mx, __shfl_xor(mx, m));
            float pe = __expf(s - mx);  // lanes >= 50 give 0
            float sm = pe;
#pragma unroll
            for (int m = 32; m >= 1; m >>= 1) sm += __shfl_xor(sm, m);
            qp[l * 68 + lane] = pe / sm;
        }
        __syncthreads();
        // Y = P @ X  -> kk
        for (int l = wid; l < NL; l += 4) {
            float acc = 0.f;
            for (int m = 0; m < NL; ++m)
                acc = fmaf(qp[l * 68 + m], x[m * DD + lane], acc);
            kk[l * 68 + lane] = acc;
        }
        __syncthreads();
        // out = Y @ V.T -> x
#pragma unroll
        for (int k4 = 0; k4 < 16; ++k4) {
            float4 a = *(const float4*)(Vb + (size_t)lane * DD + 4 * k4);
            wrow[4 * k4 + 0] = a.x; wrow[4 * k4 + 1] = a.y; wrow[4 * k4 + 2] = a.z; wrow[4 * k4 + 3] = a.w;
        }
        for (int l = wid; l < NL; l += 4) {
            float acc = 0.f;
#pragma unroll
            for (int k4 = 0; k4 < 16; ++k4) {
                float4 yv = *(const float4*)&kk[l * 68 + 4 * k4];
                acc = fmaf(wrow[4 * k4 + 0], yv.x, acc);
                acc = fmaf(wrow[4 * k4 + 1], yv.y, acc);
                acc = fmaf(wrow[4 * k4 + 2], yv.z, acc);
                acc = fmaf(wrow[4 * k4 + 3], yv.w, acc);
            }
            x[l * DD + lane] = acc;
        }
        __syncthreads();
    }
    if (wid == 0) {
        float acc = 0.f;
        for (int l = 0; l < NL; ++l) acc += x[l * DD + lane];
        xsum[(size_t)bg * DD + lane] = acc;
    }
}

// ---------------------------------------------------------------- attention stack 2: B blocks over (G=4, D=64)
__global__ __launch_bounds__(64) void k_attn2(
    const float* __restrict__ xin, const float* __restrict__ Q,
    const float* __restrict__ K, const float* __restrict__ V,
    float* __restrict__ out)
{
    __shared__ __attribute__((aligned(16))) float x[NG * DD];
    const int j = threadIdx.x;
    const int b = blockIdx.x;
    for (int i = j; i < NG * DD; i += 64) x[i] = xin[(size_t)b * NG * DD + i];
    __syncthreads();
    float o[NG];
    for (int layer = 0; layer < NCL; ++layer) {
        float wrow[DD];
        float q4[NG], k4v[NG], v4[NG];
        const float* Qb = Q + (size_t)layer * DD * DD + (size_t)j * DD;
        const float* Kb = K + (size_t)layer * DD * DD + (size_t)j * DD;
        const float* Vb = V + (size_t)layer * DD * DD + (size_t)j * DD;
#pragma unroll
        for (int k4 = 0; k4 < 16; ++k4) {
            float4 a = *(const float4*)(Qb + 4 * k4);
            wrow[4 * k4 + 0] = a.x; wrow[4 * k4 + 1] = a.y; wrow[4 * k4 + 2] = a.z; wrow[4 * k4 + 3] = a.w;
        }
#pragma unroll
        for (int g = 0; g < NG; ++g) {
            float acc = 0.f;
#pragma unroll
            for (int k4 = 0; k4 < 16; ++k4) {
                float4 xv = *(const float4*)&x[g * DD + 4 * k4];
                acc = fmaf(wrow[4 * k4 + 0], xv.x, acc);
                acc = fmaf(wrow[4 * k4 + 1], xv.y, acc);
                acc = fmaf(wrow[4 * k4 + 2], xv.z, acc);
                acc = fmaf(wrow[4 * k4 + 3], xv.w, acc);
            }
            q4[g] = acc;
        }
#pragma unroll
        for (int k4 = 0; k4 < 16; ++k4) {
            float4 a = *(const float4*)(Kb + 4 * k4);
            wrow[4 * k4 + 0] = a.x; wrow[4 * k4 + 1] = a.y; wrow[4 * k4 + 2] = a.z; wrow[4 * k4 + 3] = a.w;
        }
#pragma unroll
        for (int g = 0; g < NG; ++g) {
            float acc = 0.f;
#pragma unroll
            for (int k4 = 0; k4 < 16; ++k4) {
                float4 xv = *(const float4*)&x[g * DD + 4 * k4];
                acc = fmaf(wrow[4 * k4 + 0], xv.x, acc);
                acc = fmaf(wrow[4 * k4 + 1], xv.y, acc);
                acc = fmaf(wrow[4 * k4 + 2], xv.z, acc);
                acc = fmaf(wrow[4 * k4 + 3], xv.w, acc);
            }
            k4v[g] = acc;
        }
#pragma unroll
        for (int k4 = 0; k4 < 16; ++k4) {
            float4 a = *(const float4*)(Vb + 4 * k4);
            wrow[4 * k4 + 0] = a.x; wrow[4 * k4 + 1] = a.y; wrow[4 * k4 + 2] = a.z; wrow[4 * k4 + 3] = a.w;
        }
#pragma unroll
        for (int g = 0; g < NG; ++g) {
            float acc = 0.f;
#pragma unroll
            for (int k4 = 0; k4 < 16; ++k4) {
                float4 xv = *(const float4*)&x[g * DD + 4 * k4];
                acc = fmaf(wrow[4 * k4 + 0], xv.x, acc);
                acc = fmaf(wrow[4 * k4 + 1], xv.y, acc);
                acc = fmaf(wrow[4 * k4 + 2], xv.z, acc);
                acc = fmaf(wrow[4 * k4 + 3], xv.w, acc);
            }
            v4[g] = acc;
        }
        // scores via full-wave reduction over the feature lanes
        float p[NG][NG];
#pragma unroll
        for (int l = 0; l < NG; ++l) {
#pragma unroll
            for (int m = 0; m < NG; ++m) {
                float t = q4[l] * k4v[m];
#pragma unroll
                for (int mk = 32; mk >= 1; mk >>= 1) t += __shfl_xor(t, mk);
                p[l][m] = t * 0.125f;
            }
        }
#pragma unroll
        for (int l = 0; l < NG; ++l) {
            float mx = fmaxf(fmaxf(p[l][0], p[l][1]), fmaxf(p[l][2], p[l][3]));
            float e0 = __expf(p[l][0] - mx), e1 = __expf(p[l][1] - mx);
            float e2 = __expf(p[l][2] - mx), e3 = __expf(p[l][3] - mx);
            float inv = 1.f / (e0 + e1 + e2 + e3);
            o[l] = (e0 * v4[0] + e1 * v4[1] + e2 * v4[2] + e3 * v4[3]) * inv;
        }
        __syncthreads();
#pragma unroll
        for (int l = 0; l < NG; ++l) x[l * DD + j] = o[l];
        __syncthreads();
    }
    out[(size_t)b * DD + j] = o[0] + o[1] + o[2] + o[3];
}

// ---------------------------------------------------------------- host
extern "C" void kernel_launch(void* const* d_in, const int* in_sizes, int n_in,
                              void* d_out, int out_size, void* d_ws, size_t ws_size,
                              hipStream_t stream)
{
    const int*   src  = (const int*)  d_in[0];
    const int*   dst  = (const int*)  d_in[1];
    const float* ew   = (const float*)d_in[2];
    const float* emb  = (const float*)d_in[3];
    const float* Ws1  = (const float*)d_in[4];
    const float* Wn1  = (const float*)d_in[5];
    const float* b1   = (const float*)d_in[6];
    const float* Ws2  = (const float*)d_in[7];
    const float* Wn2  = (const float*)d_in[8];
    const float* b2   = (const float*)d_in[9];
    const float* Q1   = (const float*)d_in[10];
    const float* K1   = (const float*)d_in[11];
    const float* V1   = (const float*)d_in[12];
    const float* Q2   = (const float*)d_in[13];
    const float* K2   = (const float*)d_in[14];
    const float* V2   = (const float*)d_in[15];
    const int*   cand = (const int*)  d_in[16];
    float* out = (float*)d_out;

    auto padded = [](size_t b) { return (b + 255) & ~(size_t)255; };
    auto need = [&](int GG) -> size_t {
        size_t s = 0;
        s += padded((size_t)GG * (NN + 1) * 4);   // cnt
        s += padded((size_t)GG * 64 * 4);         // partials
        s += padded((size_t)GG * (NN + 1) * 4);   // row_off
        s += padded((size_t)GG * NN * 4);         // cursor
        s += padded((size_t)GG * NE * 8);         // packed edges
        s += padded((size_t)GG * NN * DD * 4);    // h
        s += padded((size_t)NB_ * NG * NL * DD * 4); // sel
        s += padded((size_t)NB_ * NG * DD * 4);      // xsum
        s += padded((size_t)GG * NN * 4);         // mark
        s += padded((size_t)GG * 64 * 4);         // partc
        s += padded((size_t)GG * NN * 4);         // list
        s += padded((size_t)GG * 64 * 4);         // nlist
        return s;
    };
    const int GG = (ws_size >= need(4)) ? 4 : 1;

    char* p = (char*)d_ws;
    auto alloc = [&](size_t b) -> void* { void* r = (void*)p; p += padded(b); return r; };
    int*   cnt  = (int*)  alloc((size_t)GG * (NN + 1) * 4);
    int*   part = (int*)  alloc((size_t)GG * 64 * 4);
    int*   roff = (int*)  alloc((size_t)GG * (NN + 1) * 4);
    int*   cur  = (int*)  alloc((size_t)GG * NN * 4);
    int2*  edg  = (int2*) alloc((size_t)GG * NE * 8);
    float* hb   = (float*)alloc((size_t)GG * NN * DD * 4);
    float* sel  = (float*)alloc((size_t)NB_ * NG * NL * DD * 4);
    float* xsum = (float*)alloc((size_t)NB_ * NG * DD * 4);
    int*   mark = (int*)  alloc((size_t)GG * NN * 4);
    int*   prtc = (int*)  alloc((size_t)GG * 64 * 4);
    int*   list = (int*)  alloc((size_t)GG * NN * 4);
    int*   nlst = (int*)  alloc((size_t)GG * 64 * 4);

    const int QB = (NE / 4 + 255) / 256;  // 4-edge-per-thread blocks
    for (int g0 = 0; g0 < NG; g0 += GG) {
        hipMemsetAsync(cnt, 0, (size_t)GG * (NN + 1) * 4, stream);
        hipMemsetAsync(mark, 0, (size_t)GG * NN * 4, stream);
        k_hist   <<<dim3(QB, GG), 256, 0, stream>>>(dst, cnt, g0);
        k_scan1  <<<dim3(SCAN_NB, GG), 256, 0, stream>>>(cnt, part);
        k_scan2  <<<dim3(1, GG), 64, 0, stream>>>(part, roff);
        k_scan3  <<<dim3(SCAN_NB, GG), 256, 0, stream>>>(cnt, part, roff, cur);
        k_scatter<<<dim3(QB, GG), 256, 0, stream>>>(src, dst, ew, cur, edg, g0);
        k_mark   <<<dim3((NB_ * NL) / 4, GG), 256, 0, stream>>>(roff, edg, cand, mark, g0);
        k_cscan1 <<<dim3(SCAN_NB, GG), 256, 0, stream>>>(mark, prtc);
        k_cscan2 <<<dim3(1, GG), 64, 0, stream>>>(prtc, nlst);
        k_cscan3 <<<dim3(SCAN_NB, GG), 256, 0, stream>>>(mark, prtc, list);
        k_conv_full<<<dim3(1024, GG), 256, 0, stream>>>(emb, roff, edg, Ws1, Wn1, b1, hb, list, nlst, g0);
        k_conv_cand<<<dim3((NB_ * NL) / 4, GG), 256, 0, stream>>>(hb, roff, edg, Ws2, Wn2, b2, cand, sel, g0);
    }
    k_attn1<<<NB_ * NG, 256, 0, stream>>>(sel, Q1, K1, V1, xsum);
    k_attn2<<<NB_, 64, 0, stream>>>(xsum, Q2, K2, V2, out);
}

// Round 5
// 496.405 us; speedup vs baseline: 14.4312x; 1.9611x over previous
//
#include <hip/hip_runtime.h>
#include <cstdint>
#include <cstddef>
#include <cmath>

#define NN   100000   // nodes per graph
#define NE   1600000  // edges per graph
#define DD   64       // feature dim
#define NG   4        // graphs
#define NB_  32       // batch
#define NL   50       // candidate list length
#define NCL  2        // attention layers per stack
#define SCAN_NB 49    // ceil(NN/2048)

// ---------------------------------------------------------------- mark candidates
__global__ __launch_bounds__(256) void k_candmark(const int* __restrict__ cand,
                                                  int* __restrict__ candbm,
                                                  int* __restrict__ mark, int g0) {
    const int gy = blockIdx.y;
    const int g = g0 + gy;
    int t = blockIdx.x * 256 + threadIdx.x;
    if (t < NB_ * NL) {
        int b = t / NL, l = t - b * NL;
        int n = cand[((size_t)b * NG + g) * NL + l];
        candbm[(size_t)gy * NN + n] = 1;
        mark[(size_t)gy * NN + n] = 1;
    }
}

// stream edges: sources feeding a candidate need h -> mark them
__global__ __launch_bounds__(256) void k_mark2(const int* __restrict__ src,
                                               const int* __restrict__ dst,
                                               const int* __restrict__ candbm,
                                               int* __restrict__ mark, int g0) {
    const int gy = blockIdx.y;
    const int g = g0 + gy;
    int q = blockIdx.x * 256 + threadIdx.x;
    if (q < NE / 4) {
        int4 dv = ((const int4*)(dst + (size_t)g * NE))[q];
        int4 sv = ((const int4*)(src + (size_t)g * NE))[q];
        const int* cb = candbm + (size_t)gy * NN;
        int* mk = mark + (size_t)gy * NN;
        if (cb[dv.x]) mk[sv.x] = 1;
        if (cb[dv.y]) mk[sv.y] = 1;
        if (cb[dv.z]) mk[sv.z] = 1;
        if (cb[dv.w]) mk[sv.w] = 1;
    }
}

// ---------------------------------------------------------------- compact marked -> list + rank
__global__ __launch_bounds__(256) void k_cscan1(const int* __restrict__ mark,
                                                int* __restrict__ partc) {
    const int gy = blockIdx.y;
    const int* m = mark + (size_t)gy * NN;
    __shared__ int sh[256];
    const int tid = threadIdx.x;
    int base = blockIdx.x * 2048 + tid * 8;
    int s = 0;
    for (int i = 0; i < 8; ++i) { int idx = base + i; if (idx < NN) s += m[idx]; }
    sh[tid] = s; __syncthreads();
    for (int off = 128; off > 0; off >>= 1) {
        if (tid < off) sh[tid] += sh[tid + off];
        __syncthreads();
    }
    if (tid == 0) partc[gy * 64 + blockIdx.x] = sh[0];
}

__global__ __launch_bounds__(64) void k_cscan2(int* __restrict__ partc,
                                               int* __restrict__ nlist) {
    const int gy = blockIdx.y;
    if (threadIdx.x == 0) {
        int* p = partc + gy * 64;
        int run = 0;
        for (int i = 0; i < SCAN_NB; ++i) { int t = p[i]; p[i] = run; run += t; }
        nlist[gy] = run;
    }
}

__global__ __launch_bounds__(256) void k_cscan3(const int* __restrict__ mark,
                                                const int* __restrict__ partc,
                                                int* __restrict__ list,
                                                int* __restrict__ rank) {
    const int gy = blockIdx.y;
    const int* m = mark + (size_t)gy * NN;
    int* li = list + (size_t)gy * NN;
    int* rk = rank + (size_t)gy * NN;
    __shared__ int sh[256];
    const int tid = threadIdx.x;
    int base = blockIdx.x * 2048 + tid * 8;
    int vals[8];
    int s = 0;
    for (int i = 0; i < 8; ++i) {
        int idx = base + i;
        int v = (idx < NN) ? m[idx] : 0;
        vals[i] = v; s += v;
    }
    sh[tid] = s; __syncthreads();
    for (int off = 1; off < 256; off <<= 1) {
        int t = (tid >= off) ? sh[tid - off] : 0;
        __syncthreads();
        sh[tid] += t;
        __syncthreads();
    }
    int excl = sh[tid] - s;
    int run = partc[gy * 64 + blockIdx.x] + excl;
    for (int i = 0; i < 8; ++i) {
        int idx = base + i;
        if (idx < NN) {
            if (vals[i]) { li[run] = idx; rk[idx] = run + 1; ++run; }
            else rk[idx] = 0;
        }
    }
}

// ---------------------------------------------------------------- compact CSR build (marked dsts only)
__global__ __launch_bounds__(256) void k_hist2(const int* __restrict__ dst,
                                               const int* __restrict__ rank,
                                               int* __restrict__ cnt, int g0) {
    const int gy = blockIdx.y;
    const int g = g0 + gy;
    int q = blockIdx.x * 256 + threadIdx.x;
    if (q < NE / 4) {
        int4 dv = ((const int4*)(dst + (size_t)g * NE))[q];
        const int* rk = rank + (size_t)gy * NN;
        int* c = cnt + (size_t)gy * (NN + 1);
        int r0 = rk[dv.x] - 1; if (r0 >= 0) atomicAdd(&c[r0], 1);
        int r1 = rk[dv.y] - 1; if (r1 >= 0) atomicAdd(&c[r1], 1);
        int r2 = rk[dv.z] - 1; if (r2 >= 0) atomicAdd(&c[r2], 1);
        int r3 = rk[dv.w] - 1; if (r3 >= 0) atomicAdd(&c[r3], 1);
    }
}

__global__ __launch_bounds__(256) void k_scan1(const int* __restrict__ cnt,
                                               int* __restrict__ part) {
    const int gy = blockIdx.y;
    const int* c = cnt + (size_t)gy * (NN + 1);
    __shared__ int sh[256];
    const int tid = threadIdx.x;
    int base = blockIdx.x * 2048 + tid * 8;
    int s = 0;
    for (int i = 0; i < 8; ++i) { int idx = base + i; if (idx < NN) s += c[idx]; }
    sh[tid] = s; __syncthreads();
    for (int off = 128; off > 0; off >>= 1) {
        if (tid < off) sh[tid] += sh[tid + off];
        __syncthreads();
    }
    if (tid == 0) part[gy * 64 + blockIdx.x] = sh[0];
}

__global__ __launch_bounds__(64) void k_scan2(int* __restrict__ part,
                                              int* __restrict__ row_off) {
    const int gy = blockIdx.y;
    if (threadIdx.x == 0) {
        int* p = part + gy * 64;
        int run = 0;
        for (int i = 0; i < SCAN_NB; ++i) { int t = p[i]; p[i] = run; run += t; }
        row_off[(size_t)gy * (NN + 1) + NN] = run;
    }
}

__global__ __launch_bounds__(256) void k_scan3(const int* __restrict__ cnt,
                                               const int* __restrict__ part,
                                               int* __restrict__ row_off,
                                               int* __restrict__ cursor) {
    const int gy = blockIdx.y;
    const int* c = cnt + (size_t)gy * (NN + 1);
    int* ro = row_off + (size_t)gy * (NN + 1);
    int* cu = cursor + (size_t)gy * NN;
    __shared__ int sh[256];
    const int tid = threadIdx.x;
    int base = blockIdx.x * 2048 + tid * 8;
    int vals[8];
    int s = 0;
    for (int i = 0; i < 8; ++i) {
        int idx = base + i;
        int v = (idx < NN) ? c[idx] : 0;
        vals[i] = v; s += v;
    }
    sh[tid] = s; __syncthreads();
    for (int off = 1; off < 256; off <<= 1) {
        int t = (tid >= off) ? sh[tid - off] : 0;
        __syncthreads();
        sh[tid] += t;
        __syncthreads();
    }
    int excl = sh[tid] - s;
    int run = part[gy * 64 + blockIdx.x] + excl;
    for (int i = 0; i < 8; ++i) {
        int idx = base + i;
        if (idx < NN) { ro[idx] = run; cu[idx] = run; run += vals[i]; }
    }
}

// scatter only edges whose dst is marked, into the compact CSR
__global__ __launch_bounds__(256) void k_scatter2(const int* __restrict__ src,
                                                  const int* __restrict__ dst,
                                                  const float* __restrict__ ew,
                                                  const int* __restrict__ rank,
                                                  int* __restrict__ cursor,
                                                  int2* __restrict__ ed, int g0) {
    const int gy = blockIdx.y;
    const int g = g0 + gy;
    int q = blockIdx.x * 256 + threadIdx.x;
    if (q < NE / 4) {
        int4   dv = ((const int4*)(dst + (size_t)g * NE))[q];
        int4   sv = ((const int4*)(src + (size_t)g * NE))[q];
        float4 wv = ((const float4*)(ew + (size_t)g * NE))[q];
        const int* rk = rank + (size_t)gy * NN;
        int* cu = cursor + (size_t)gy * NN;
        int2* eg = ed + (size_t)gy * NE;
        int r0 = rk[dv.x] - 1; if (r0 >= 0) { int p = atomicAdd(&cu[r0], 1); eg[p] = make_int2(sv.x, __float_as_int(wv.x)); }
        int r1 = rk[dv.y] - 1; if (r1 >= 0) { int p = atomicAdd(&cu[r1], 1); eg[p] = make_int2(sv.y, __float_as_int(wv.y)); }
        int r2 = rk[dv.z] - 1; if (r2 >= 0) { int p = atomicAdd(&cu[r2], 1); eg[p] = make_int2(sv.z, __float_as_int(wv.z)); }
        int r3 = rk[dv.w] - 1; if (r3 >= 0) { int p = atomicAdd(&cu[r3], 1); eg[p] = make_int2(sv.w, __float_as_int(wv.w)); }
    }
}

// ---------------------------------------------------------------- fused SAGE conv (layer 1, relu) over compact rows
__global__ __launch_bounds__(256) void k_conv_full(
    const float* __restrict__ emb, const int* __restrict__ row_off,
    const int2* __restrict__ edges,
    const float* __restrict__ Wsf, const float* __restrict__ Wng,
    const float* __restrict__ bias, float* __restrict__ outh,
    const int* __restrict__ list, const int* __restrict__ nlist, int g0)
{
    const int gy = blockIdx.y;
    const int g = g0 + gy;
    const float* feat = emb + (size_t)g * NN * DD;
    const int* ro = row_off + (size_t)gy * (NN + 1);
    const int2* ed = edges + (size_t)gy * NE;
    const int* li = list + (size_t)gy * NN;
    float* og = outh + (size_t)gy * NN * DD;   // indexed by compact row
    const int lane = threadIdx.x & 63;
    const int wid = threadIdx.x >> 6;

    float wsr[DD], wnr[DD];
    {
        const float* wsp = Wsf + (size_t)g * DD * DD + (size_t)lane * DD;
        const float* wnp = Wng + (size_t)g * DD * DD + (size_t)lane * DD;
#pragma unroll
        for (int k4 = 0; k4 < 16; ++k4) {
            float4 a = *(const float4*)(wsp + 4 * k4);
            wsr[4 * k4 + 0] = a.x; wsr[4 * k4 + 1] = a.y; wsr[4 * k4 + 2] = a.z; wsr[4 * k4 + 3] = a.w;
            float4 c = *(const float4*)(wnp + 4 * k4);
            wnr[4 * k4 + 0] = c.x; wnr[4 * k4 + 1] = c.y; wnr[4 * k4 + 2] = c.z; wnr[4 * k4 + 3] = c.w;
        }
    }
    const float bv = bias[(size_t)g * DD + lane];

    __shared__ __attribute__((aligned(16))) float fs[4][DD];
    __shared__ __attribute__((aligned(16))) float ns[4][DD];

    const int nl = nlist[gy];
    const int wglob = blockIdx.x * 4 + wid;
    const int wstep = gridDim.x * 4;
    for (int t = wglob; t < nl; t += wstep) {
        const int n = li[t];
        const int e0 = ro[t], e1 = ro[t + 1];
        const float fself = feat[(size_t)n * DD + lane];
        float acc = 0.f;
        for (int base = e0; base < e1; base += 64) {
            const int cnt = min(e1 - base, 64);
            int   myS = 0;
            float myW = 0.f;
            if (lane < cnt) {
                int2 r = ed[base + lane];
                myS = r.x; myW = __int_as_float(r.y);
            }
            for (int j = 0; j < cnt; j += 8) {
                float fv[8], wv[8];
#pragma unroll
                for (int u = 0; u < 8; ++u) {
                    int s = __shfl(myS, j + u);
                    wv[u] = __shfl(myW, j + u);
                    fv[u] = feat[(size_t)s * DD + lane];
                }
#pragma unroll
                for (int u = 0; u < 8; ++u) acc = fmaf(fv[u], wv[u], acc);
            }
        }
        float neigh = acc / fmaxf((float)(e1 - e0), 1.f);
        fs[wid][lane] = fself;
        ns[wid][lane] = neigh;
        float o = bv;
#pragma unroll
        for (int k4 = 0; k4 < 16; ++k4) {
            float4 f = *(const float4*)&fs[wid][4 * k4];
            float4 nv = *(const float4*)&ns[wid][4 * k4];
            o = fmaf(wsr[4 * k4 + 0], f.x, o);
            o = fmaf(wsr[4 * k4 + 1], f.y, o);
            o = fmaf(wsr[4 * k4 + 2], f.z, o);
            o = fmaf(wsr[4 * k4 + 3], f.w, o);
            o = fmaf(wnr[4 * k4 + 0], nv.x, o);
            o = fmaf(wnr[4 * k4 + 1], nv.y, o);
            o = fmaf(wnr[4 * k4 + 2], nv.z, o);
            o = fmaf(wnr[4 * k4 + 3], nv.w, o);
        }
        o = fmaxf(o, 0.f);  // relu
        og[(size_t)t * DD + lane] = o;
    }
}

// ---------------------------------------------------------------- fused SAGE conv at candidates (layer 2), h indexed via rank
__global__ __launch_bounds__(256) void k_conv_cand(
    const float* __restrict__ hfeat, const int* __restrict__ row_off,
    const int2* __restrict__ edges, const int* __restrict__ rank,
    const float* __restrict__ Wsf, const float* __restrict__ Wng,
    const float* __restrict__ bias, const int* __restrict__ cand,
    float* __restrict__ sel, int g0)
{
    const int gy = blockIdx.y;
    const int g = g0 + gy;
    const float* feat = hfeat + (size_t)gy * NN * DD;   // compact-row indexed
    const int* ro = row_off + (size_t)gy * (NN + 1);
    const int2* ed = edges + (size_t)gy * NE;
    const int* rk = rank + (size_t)gy * NN;
    const int lane = threadIdx.x & 63;
    const int wid = threadIdx.x >> 6;

    float wsr[DD], wnr[DD];
    {
        const float* wsp = Wsf + (size_t)g * DD * DD + (size_t)lane * DD;
        const float* wnp = Wng + (size_t)g * DD * DD + (size_t)lane * DD;
#pragma unroll
        for (int k4 = 0; k4 < 16; ++k4) {
            float4 a = *(const float4*)(wsp + 4 * k4);
            wsr[4 * k4 + 0] = a.x; wsr[4 * k4 + 1] = a.y; wsr[4 * k4 + 2] = a.z; wsr[4 * k4 + 3] = a.w;
            float4 c = *(const float4*)(wnp + 4 * k4);
            wnr[4 * k4 + 0] = c.x; wnr[4 * k4 + 1] = c.y; wnr[4 * k4 + 2] = c.z; wnr[4 * k4 + 3] = c.w;
        }
    }
    const float bv = bias[(size_t)g * DD + lane];

    __shared__ __attribute__((aligned(16))) float fs[4][DD];
    __shared__ __attribute__((aligned(16))) float nsh[4][DD];

    int t = blockIdx.x * 4 + wid;  // 0..1599
    if (t < NB_ * NL) {
        int b = t / NL;
        int l = t - b * NL;
        int n = cand[((size_t)b * NG + g) * NL + l];
        const int rc = rk[n] - 1;             // candidate is marked
        const int e0 = ro[rc], e1 = ro[rc + 1];
        const float fself = feat[(size_t)rc * DD + lane];
        float acc = 0.f;
        for (int base = e0; base < e1; base += 64) {
            const int cnt = min(e1 - base, 64);
            int   myS = 0;
            float myW = 0.f;
            if (lane < cnt) {
                int2 r = ed[base + lane];
                myS = rk[r.x] - 1;            // sources of candidates are marked
                myW = __int_as_float(r.y);
            }
            for (int j = 0; j < cnt; j += 8) {
                float fv[8], wv[8];
#pragma unroll
                for (int u = 0; u < 8; ++u) {
                    int s = __shfl(myS, j + u);
                    wv[u] = __shfl(myW, j + u);
                    fv[u] = feat[(size_t)max(s, 0) * DD + lane];
                }
#pragma unroll
                for (int u = 0; u < 8; ++u) acc = fmaf(fv[u], wv[u], acc);
            }
        }
        float neigh = acc / fmaxf((float)(e1 - e0), 1.f);
        fs[wid][lane] = fself;
        nsh[wid][lane] = neigh;
        float o = bv;
#pragma unroll
        for (int k4 = 0; k4 < 16; ++k4) {
            float4 f = *(const float4*)&fs[wid][4 * k4];
            float4 nv = *(const float4*)&nsh[wid][4 * k4];
            o = fmaf(wsr[4 * k4 + 0], f.x, o);
            o = fmaf(wsr[4 * k4 + 1], f.y, o);
            o = fmaf(wsr[4 * k4 + 2], f.z, o);
            o = fmaf(wsr[4 * k4 + 3], f.w, o);
            o = fmaf(wnr[4 * k4 + 0], nv.x, o);
            o = fmaf(wnr[4 * k4 + 1], nv.y, o);
            o = fmaf(wnr[4 * k4 + 2], nv.z, o);
            o = fmaf(wnr[4 * k4 + 3], nv.w, o);
        }
        sel[(((size_t)b * NG + g) * NL + l) * DD + lane] = o;  // no relu
    }
}

// ---------------------------------------------------------------- attention stack 1: (B*G) blocks over (L=50, D=64)
__global__ __launch_bounds__(256) void k_attn1(
    const float* __restrict__ sel, const float* __restrict__ Q,
    const float* __restrict__ K, const float* __restrict__ V,
    float* __restrict__ xsum)
{
    __shared__ __attribute__((aligned(16))) float x[NL * DD];
    __shared__ __attribute__((aligned(16))) float qp[NL * 68];
    __shared__ __attribute__((aligned(16))) float kk[NL * 68];
    const int tid = threadIdx.x;
    const int lane = tid & 63;
    const int wid = tid >> 6;
    const int bg = blockIdx.x;
    const float* xin = sel + (size_t)bg * NL * DD;
    for (int i = tid; i < NL * DD; i += 256) x[i] = xin[i];
    __syncthreads();

    for (int layer = 0; layer < NCL; ++layer) {
        const float* Qb = Q + (size_t)layer * DD * DD;
        const float* Kb = K + (size_t)layer * DD * DD;
        const float* Vb = V + (size_t)layer * DD * DD;
        float wrow[DD];
#pragma unroll
        for (int k4 = 0; k4 < 16; ++k4) {
            float4 a = *(const float4*)(Qb + (size_t)lane * DD + 4 * k4);
            wrow[4 * k4 + 0] = a.x; wrow[4 * k4 + 1] = a.y; wrow[4 * k4 + 2] = a.z; wrow[4 * k4 + 3] = a.w;
        }
        for (int l = wid; l < NL; l += 4) {
            float acc = 0.f;
#pragma unroll
            for (int k4 = 0; k4 < 16; ++k4) {
                float4 xv = *(const float4*)&x[l * DD + 4 * k4];
                acc = fmaf(wrow[4 * k4 + 0], xv.x, acc);
                acc = fmaf(wrow[4 * k4 + 1], xv.y, acc);
                acc = fmaf(wrow[4 * k4 + 2], xv.z, acc);
                acc = fmaf(wrow[4 * k4 + 3], xv.w, acc);
            }
            qp[l * 68 + lane] = acc;
        }
#pragma unroll
        for (int k4 = 0; k4 < 16; ++k4) {
            float4 a = *(const float4*)(Kb + (size_t)lane * DD + 4 * k4);
            wrow[4 * k4 + 0] = a.x; wrow[4 * k4 + 1] = a.y; wrow[4 * k4 + 2] = a.z; wrow[4 * k4 + 3] = a.w;
        }
        for (int l = wid; l < NL; l += 4) {
            float acc = 0.f;
#pragma unroll
            for (int k4 = 0; k4 < 16; ++k4) {
                float4 xv = *(const float4*)&x[l * DD + 4 * k4];
                acc = fmaf(wrow[4 * k4 + 0], xv.x, acc);
                acc = fmaf(wrow[4 * k4 + 1], xv.y, acc);
                acc = fmaf(wrow[4 * k4 + 2], xv.z, acc);
                acc = fmaf(wrow[4 * k4 + 3], xv.w, acc);
            }
            kk[l * 68 + lane] = acc;
        }
        __syncthreads();
        for (int l = wid; l < NL; l += 4) {
            float s;
            if (lane < NL) {
                float acc = 0.f;
#pragma unroll
                for (int k4 = 0; k4 < 16; ++k4) {
                    float4 qv = *(const float4*)&qp[l * 68 + 4 * k4];
                    float4 kv = *(const float4*)&kk[lane * 68 + 4 * k4];
                    acc += qv.x * kv.x + qv.y * kv.y + qv.z * kv.z + qv.w * kv.w;
                }
                s = acc * 0.125f;
            } else {
                s = -INFINITY;
            }
            float mx = s;
#pragma unroll
            for (int m = 32; m >= 1; m >>= 1) mx = fmaxf(mx, __shfl_xor(mx, m));
            float pe = __expf(s - mx);
            float sm = pe;
#pragma unroll
            for (int m = 32; m >= 1; m >>= 1) sm += __shfl_xor(sm, m);
            qp[l * 68 + lane] = pe / sm;
        }
        __syncthreads();
        for (int l = wid; l < NL; l += 4) {
            float acc = 0.f;
            for (int m = 0; m < NL; ++m)
                acc = fmaf(qp[l * 68 + m], x[m * DD + lane], acc);
            kk[l * 68 + lane] = acc;
        }
        __syncthreads();
#pragma unroll
        for (int k4 = 0; k4 < 16; ++k4) {
            float4 a = *(const float4*)(Vb + (size_t)lane * DD + 4 * k4);
            wrow[4 * k4 + 0] = a.x; wrow[4 * k4 + 1] = a.y; wrow[4 * k4 + 2] = a.z; wrow[4 * k4 + 3] = a.w;
        }
        for (int l = wid; l < NL; l += 4) {
            float acc = 0.f;
#pragma unroll
            for (int k4 = 0; k4 < 16; ++k4) {
                float4 yv = *(const float4*)&kk[l * 68 + 4 * k4];
                acc = fmaf(wrow[4 * k4 + 0], yv.x, acc);
                acc = fmaf(wrow[4 * k4 + 1], yv.y, acc);
                acc = fmaf(wrow[4 * k4 + 2], yv.z, acc);
                acc = fmaf(wrow[4 * k4 + 3], yv.w, acc);
            }
            x[l * DD + lane] = acc;
        }
        __syncthreads();
    }
    if (wid == 0) {
        float acc = 0.f;
        for (int l = 0; l < NL; ++l) acc += x[l * DD + lane];
        xsum[(size_t)bg * DD + lane] = acc;
    }
}

// ---------------------------------------------------------------- attention stack 2: B blocks over (G=4, D=64)
__global__ __launch_bounds__(64) void k_attn2(
    const float* __restrict__ xin, const float* __restrict__ Q,
    const float* __restrict__ K, const float* __restrict__ V,
    float* __restrict__ out)
{
    __shared__ __attribute__((aligned(16))) float x[NG * DD];
    const int j = threadIdx.x;
    const int b = blockIdx.x;
    for (int i = j; i < NG * DD; i += 64) x[i] = xin[(size_t)b * NG * DD + i];
    __syncthreads();
    float o[NG];
    for (int layer = 0; layer < NCL; ++layer) {
        float wrow[DD];
        float q4[NG], k4v[NG], v4[NG];
        const float* Qb = Q + (size_t)layer * DD * DD + (size_t)j * DD;
        const float* Kb = K + (size_t)layer * DD * DD + (size_t)j * DD;
        const float* Vb = V + (size_t)layer * DD * DD + (size_t)j * DD;
#pragma unroll
        for (int k4 = 0; k4 < 16; ++k4) {
            float4 a = *(const float4*)(Qb + 4 * k4);
            wrow[4 * k4 + 0] = a.x; wrow[4 * k4 + 1] = a.y; wrow[4 * k4 + 2] = a.z; wrow[4 * k4 + 3] = a.w;
        }
#pragma unroll
        for (int g = 0; g < NG; ++g) {
            float acc = 0.f;
#pragma unroll
            for (int k4 = 0; k4 < 16; ++k4) {
                float4 xv = *(const float4*)&x[g * DD + 4 * k4];
                acc = fmaf(wrow[4 * k4 + 0], xv.x, acc);
                acc = fmaf(wrow[4 * k4 + 1], xv.y, acc);
                acc = fmaf(wrow[4 * k4 + 2], xv.z, acc);
                acc = fmaf(wrow[4 * k4 + 3], xv.w, acc);
            }
            q4[g] = acc;
        }
#pragma unroll
        for (int k4 = 0; k4 < 16; ++k4) {
            float4 a = *(const float4*)(Kb + 4 * k4);
            wrow[4 * k4 + 0] = a.x; wrow[4 * k4 + 1] = a.y; wrow[4 * k4 + 2] = a.z; wrow[4 * k4 + 3] = a.w;
        }
#pragma unroll
        for (int g = 0; g < NG; ++g) {
            float acc = 0.f;
#pragma unroll
            for (int k4 = 0; k4 < 16; ++k4) {
                float4 xv = *(const float4*)&x[g * DD + 4 * k4];
                acc = fmaf(wrow[4 * k4 + 0], xv.x, acc);
                acc = fmaf(wrow[4 * k4 + 1], xv.y, acc);
                acc = fmaf(wrow[4 * k4 + 2], xv.z, acc);
                acc = fmaf(wrow[4 * k4 + 3], xv.w, acc);
            }
            k4v[g] = acc;
        }
#pragma unroll
        for (int k4 = 0; k4 < 16; ++k4) {
            float4 a = *(const float4*)(Vb + 4 * k4);
            wrow[4 * k4 + 0] = a.x; wrow[4 * k4 + 1] = a.y; wrow[4 * k4 + 2] = a.z; wrow[4 * k4 + 3] = a.w;
        }
#pragma unroll
        for (int g = 0; g < NG; ++g) {
            float acc = 0.f;
#pragma unroll
            for (int k4 = 0; k4 < 16; ++k4) {
                float4 xv = *(const float4*)&x[g * DD + 4 * k4];
                acc = fmaf(wrow[4 * k4 + 0], xv.x, acc);
                acc = fmaf(wrow[4 * k4 + 1], xv.y, acc);
                acc = fmaf(wrow[4 * k4 + 2], xv.z, acc);
                acc = fmaf(wrow[4 * k4 + 3], xv.w, acc);
            }
            v4[g] = acc;
        }
        float p[NG][NG];
#pragma unroll
        for (int l = 0; l < NG; ++l) {
#pragma unroll
            for (int m = 0; m < NG; ++m) {
                float t = q4[l] * k4v[m];
#pragma unroll
                for (int mk = 32; mk >= 1; mk >>= 1) t += __shfl_xor(t, mk);
                p[l][m] = t * 0.125f;
            }
        }
#pragma unroll
        for (int l = 0; l < NG; ++l) {
            float mx = fmaxf(fmaxf(p[l][0], p[l][1]), fmaxf(p[l][2], p[l][3]));
            float e0 = __expf(p[l][0] - mx), e1 = __expf(p[l][1] - mx);
            float e2 = __expf(p[l][2] - mx), e3 = __expf(p[l][3] - mx);
            float inv = 1.f / (e0 + e1 + e2 + e3);
            o[l] = (e0 * v4[0] + e1 * v4[1] + e2 * v4[2] + e3 * v4[3]) * inv;
        }
        __syncthreads();
#pragma unroll
        for (int l = 0; l < NG; ++l) x[l * DD + j] = o[l];
        __syncthreads();
    }
    out[(size_t)b * DD + j] = o[0] + o[1] + o[2] + o[3];
}

// ---------------------------------------------------------------- host
extern "C" void kernel_launch(void* const* d_in, const int* in_sizes, int n_in,
                              void* d_out, int out_size, void* d_ws, size_t ws_size,
                              hipStream_t stream)
{
    const int*   src  = (const int*)  d_in[0];
    const int*   dst  = (const int*)  d_in[1];
    const float* ew   = (const float*)d_in[2];
    const float* emb  = (const float*)d_in[3];
    const float* Ws1  = (const float*)d_in[4];
    const float* Wn1  = (const float*)d_in[5];
    const float* b1   = (const float*)d_in[6];
    const float* Ws2  = (const float*)d_in[7];
    const float* Wn2  = (const float*)d_in[8];
    const float* b2   = (const float*)d_in[9];
    const float* Q1   = (const float*)d_in[10];
    const float* K1   = (const float*)d_in[11];
    const float* V1   = (const float*)d_in[12];
    const float* Q2   = (const float*)d_in[13];
    const float* K2   = (const float*)d_in[14];
    const float* V2   = (const float*)d_in[15];
    const int*   cand = (const int*)  d_in[16];
    float* out = (float*)d_out;

    auto padded = [](size_t b) { return (b + 255) & ~(size_t)255; };
    auto need = [&](int GG) -> size_t {
        size_t s = 0;
        s += padded((size_t)GG * (NN + 1) * 4);   // cnt
        s += padded((size_t)GG * 64 * 4);         // part
        s += padded((size_t)GG * (NN + 1) * 4);   // row_off
        s += padded((size_t)GG * NN * 4);         // cursor
        s += padded((size_t)GG * NE * 8);         // packed edges
        s += padded((size_t)GG * NN * DD * 4);    // h (compact rows)
        s += padded((size_t)NB_ * NG * NL * DD * 4); // sel
        s += padded((size_t)NB_ * NG * DD * 4);      // xsum
        s += padded((size_t)GG * NN * 4);         // candbm
        s += padded((size_t)GG * NN * 4);         // mark
        s += padded((size_t)GG * 64 * 4);         // partc
        s += padded((size_t)GG * NN * 4);         // list
        s += padded((size_t)GG * NN * 4);         // rank
        s += padded((size_t)GG * 64 * 4);         // nlist
        return s;
    };
    const int GG = (ws_size >= need(4)) ? 4 : 1;

    char* p = (char*)d_ws;
    auto alloc = [&](size_t b) -> void* { void* r = (void*)p; p += padded(b); return r; };
    int*   cnt  = (int*)  alloc((size_t)GG * (NN + 1) * 4);
    int*   part = (int*)  alloc((size_t)GG * 64 * 4);
    int*   roff = (int*)  alloc((size_t)GG * (NN + 1) * 4);
    int*   cur  = (int*)  alloc((size_t)GG * NN * 4);
    int2*  edg  = (int2*) alloc((size_t)GG * NE * 8);
    float* hb   = (float*)alloc((size_t)GG * NN * DD * 4);
    float* sel  = (float*)alloc((size_t)NB_ * NG * NL * DD * 4);
    float* xsum = (float*)alloc((size_t)NB_ * NG * DD * 4);
    int*   cbm  = (int*)  alloc((size_t)GG * NN * 4);
    int*   mark = (int*)  alloc((size_t)GG * NN * 4);
    int*   prtc = (int*)  alloc((size_t)GG * 64 * 4);
    int*   list = (int*)  alloc((size_t)GG * NN * 4);
    int*   rank = (int*)  alloc((size_t)GG * NN * 4);
    int*   nlst = (int*)  alloc((size_t)GG * 64 * 4);

    const int QB = (NE / 4 + 255) / 256;  // 4-edge-per-thread blocks
    const int CB = (NB_ * NL + 255) / 256;
    for (int g0 = 0; g0 < NG; g0 += GG) {
        hipMemsetAsync(cnt, 0, (size_t)GG * (NN + 1) * 4, stream);
        hipMemsetAsync(cbm, 0, (size_t)GG * NN * 4, stream);
        hipMemsetAsync(mark, 0, (size_t)GG * NN * 4, stream);
        k_candmark<<<dim3(CB, GG), 256, 0, stream>>>(cand, cbm, mark, g0);
        k_mark2   <<<dim3(QB, GG), 256, 0, stream>>>(src, dst, cbm, mark, g0);
        k_cscan1  <<<dim3(SCAN_NB, GG), 256, 0, stream>>>(mark, prtc);
        k_cscan2  <<<dim3(1, GG), 64, 0, stream>>>(prtc, nlst);
        k_cscan3  <<<dim3(SCAN_NB, GG), 256, 0, stream>>>(mark, prtc, list, rank);
        k_hist2   <<<dim3(QB, GG), 256, 0, stream>>>(dst, rank, cnt, g0);
        k_scan1   <<<dim3(SCAN_NB, GG), 256, 0, stream>>>(cnt, part);
        k_scan2   <<<dim3(1, GG), 64, 0, stream>>>(part, roff);
        k_scan3   <<<dim3(SCAN_NB, GG), 256, 0, stream>>>(cnt, part, roff, cur);
        k_scatter2<<<dim3(QB, GG), 256, 0, stream>>>(src, dst, ew, rank, cur, edg, g0);
        k_conv_full<<<dim3(512, GG), 256, 0, stream>>>(emb, roff, edg, Ws1, Wn1, b1, hb, list, nlst, g0);
        k_conv_cand<<<dim3((NB_ * NL) / 4, GG), 256, 0, stream>>>(hb, roff, edg, rank, Ws2, Wn2, b2, cand, sel, g0);
    }
    k_attn1<<<NB_ * NG, 256, 0, stream>>>(sel, Q1, K1, V1, xsum);
    k_attn2<<<NB_, 64, 0, stream>>>(xsum, Q2, K2, V2, out);
}

// Round 6
// 493.387 us; speedup vs baseline: 14.5195x; 1.0061x over previous
//
#include <hip/hip_runtime.h>
#include <cstdint>
#include <cstddef>
#include <cmath>

#define NN   100000   // nodes per graph
#define NE   1600000  // edges per graph
#define DD   64       // feature dim
#define NG   4        // graphs
#define NB_  32       // batch
#define NL   50       // candidate list length
#define NCL  2        // attention layers per stack
#define SCAN_NB 49    // ceil(NN/2048)

// ---------------------------------------------------------------- mark candidates
__global__ __launch_bounds__(256) void k_candmark(const int* __restrict__ cand,
                                                  int* __restrict__ candbm,
                                                  int* __restrict__ mark, int g0) {
    const int gy = blockIdx.y;
    const int g = g0 + gy;
    int t = blockIdx.x * 256 + threadIdx.x;
    if (t < NB_ * NL) {
        int b = t / NL, l = t - b * NL;
        int n = cand[((size_t)b * NG + g) * NL + l];
        candbm[(size_t)gy * NN + n] = 1;
        mark[(size_t)gy * NN + n] = 1;
    }
}

// stream edges: sources feeding a candidate need h -> mark them
__global__ __launch_bounds__(256) void k_mark2(const int* __restrict__ src,
                                               const int* __restrict__ dst,
                                               const int* __restrict__ candbm,
                                               int* __restrict__ mark, int g0) {
    const int gy = blockIdx.y;
    const int g = g0 + gy;
    int q = blockIdx.x * 256 + threadIdx.x;
    if (q < NE / 4) {
        int4 dv = ((const int4*)(dst + (size_t)g * NE))[q];
        int4 sv = ((const int4*)(src + (size_t)g * NE))[q];
        const int* cb = candbm + (size_t)gy * NN;
        int* mk = mark + (size_t)gy * NN;
        if (cb[dv.x]) mk[sv.x] = 1;
        if (cb[dv.y]) mk[sv.y] = 1;
        if (cb[dv.z]) mk[sv.z] = 1;
        if (cb[dv.w]) mk[sv.w] = 1;
    }
}

// ---------------------------------------------------------------- compact marked -> list + rank
__global__ __launch_bounds__(256) void k_cscan1(const int* __restrict__ mark,
                                                int* __restrict__ partc) {
    const int gy = blockIdx.y;
    const int* m = mark + (size_t)gy * NN;
    __shared__ int sh[256];
    const int tid = threadIdx.x;
    int base = blockIdx.x * 2048 + tid * 8;
    int s = 0;
    for (int i = 0; i < 8; ++i) { int idx = base + i; if (idx < NN) s += m[idx]; }
    sh[tid] = s; __syncthreads();
    for (int off = 128; off > 0; off >>= 1) {
        if (tid < off) sh[tid] += sh[tid + off];
        __syncthreads();
    }
    if (tid == 0) partc[gy * 64 + blockIdx.x] = sh[0];
}

// fused: per-block serial prefix of raw partials; last block writes nlist
__global__ __launch_bounds__(256) void k_cscan3(const int* __restrict__ mark,
                                                const int* __restrict__ partc,
                                                int* __restrict__ list,
                                                int* __restrict__ rank,
                                                int* __restrict__ nlist) {
    const int gy = blockIdx.y;
    const int* m = mark + (size_t)gy * NN;
    int* li = list + (size_t)gy * NN;
    int* rk = rank + (size_t)gy * NN;
    __shared__ int sh[256];
    __shared__ int sbase;
    const int tid = threadIdx.x;
    if (tid == 0) {
        int b = 0;
        for (int i = 0; i < blockIdx.x; ++i) b += partc[gy * 64 + i];
        sbase = b;
    }
    int base = blockIdx.x * 2048 + tid * 8;
    int vals[8];
    int s = 0;
    for (int i = 0; i < 8; ++i) {
        int idx = base + i;
        int v = (idx < NN) ? m[idx] : 0;
        vals[i] = v; s += v;
    }
    sh[tid] = s; __syncthreads();
    for (int off = 1; off < 256; off <<= 1) {
        int t = (tid >= off) ? sh[tid - off] : 0;
        __syncthreads();
        sh[tid] += t;
        __syncthreads();
    }
    int excl = sh[tid] - s;
    int run = sbase + excl;
    for (int i = 0; i < 8; ++i) {
        int idx = base + i;
        if (idx < NN) {
            if (vals[i]) { li[run] = idx; rk[idx] = run + 1; ++run; }
            else rk[idx] = 0;
        }
    }
    if (blockIdx.x == SCAN_NB - 1 && tid == 255) nlist[gy] = sbase + sh[255];
}

// ---------------------------------------------------------------- compact CSR build (marked dsts only)
__global__ __launch_bounds__(256) void k_hist2(const int* __restrict__ dst,
                                               const int* __restrict__ rank,
                                               int* __restrict__ cnt, int g0) {
    const int gy = blockIdx.y;
    const int g = g0 + gy;
    int q = blockIdx.x * 256 + threadIdx.x;
    if (q < NE / 4) {
        int4 dv = ((const int4*)(dst + (size_t)g * NE))[q];
        const int* rk = rank + (size_t)gy * NN;
        int* c = cnt + (size_t)gy * (NN + 1);
        int r0 = rk[dv.x] - 1; if (r0 >= 0) atomicAdd(&c[r0], 1);
        int r1 = rk[dv.y] - 1; if (r1 >= 0) atomicAdd(&c[r1], 1);
        int r2 = rk[dv.z] - 1; if (r2 >= 0) atomicAdd(&c[r2], 1);
        int r3 = rk[dv.w] - 1; if (r3 >= 0) atomicAdd(&c[r3], 1);
    }
}

__global__ __launch_bounds__(256) void k_scan1(const int* __restrict__ cnt,
                                               int* __restrict__ part) {
    const int gy = blockIdx.y;
    const int* c = cnt + (size_t)gy * (NN + 1);
    __shared__ int sh[256];
    const int tid = threadIdx.x;
    int base = blockIdx.x * 2048 + tid * 8;
    int s = 0;
    for (int i = 0; i < 8; ++i) { int idx = base + i; if (idx < NN) s += c[idx]; }
    sh[tid] = s; __syncthreads();
    for (int off = 128; off > 0; off >>= 1) {
        if (tid < off) sh[tid] += sh[tid + off];
        __syncthreads();
    }
    if (tid == 0) part[gy * 64 + blockIdx.x] = sh[0];
}

// fused: per-block serial prefix of raw partials
__global__ __launch_bounds__(256) void k_scan3(const int* __restrict__ cnt,
                                               const int* __restrict__ part,
                                               int* __restrict__ row_off,
                                               int* __restrict__ cursor) {
    const int gy = blockIdx.y;
    const int* c = cnt + (size_t)gy * (NN + 1);
    int* ro = row_off + (size_t)gy * (NN + 1);
    int* cu = cursor + (size_t)gy * NN;
    __shared__ int sh[256];
    __shared__ int sbase;
    const int tid = threadIdx.x;
    if (tid == 0) {
        int b = 0;
        for (int i = 0; i < blockIdx.x; ++i) b += part[gy * 64 + i];
        sbase = b;
    }
    int base = blockIdx.x * 2048 + tid * 8;
    int vals[8];
    int s = 0;
    for (int i = 0; i < 8; ++i) {
        int idx = base + i;
        int v = (idx < NN) ? c[idx] : 0;
        vals[i] = v; s += v;
    }
    sh[tid] = s; __syncthreads();
    for (int off = 1; off < 256; off <<= 1) {
        int t = (tid >= off) ? sh[tid - off] : 0;
        __syncthreads();
        sh[tid] += t;
        __syncthreads();
    }
    int excl = sh[tid] - s;
    int run = sbase + excl;
    for (int i = 0; i < 8; ++i) {
        int idx = base + i;
        if (idx < NN) { ro[idx] = run; cu[idx] = run; run += vals[i]; }
    }
}

// scatter only edges whose dst is marked, into the compact CSR
__global__ __launch_bounds__(256) void k_scatter2(const int* __restrict__ src,
                                                  const int* __restrict__ dst,
                                                  const float* __restrict__ ew,
                                                  const int* __restrict__ rank,
                                                  int* __restrict__ cursor,
                                                  int2* __restrict__ ed, int g0) {
    const int gy = blockIdx.y;
    const int g = g0 + gy;
    int q = blockIdx.x * 256 + threadIdx.x;
    if (q < NE / 4) {
        int4   dv = ((const int4*)(dst + (size_t)g * NE))[q];
        int4   sv = ((const int4*)(src + (size_t)g * NE))[q];
        float4 wv = ((const float4*)(ew + (size_t)g * NE))[q];
        const int* rk = rank + (size_t)gy * NN;
        int* cu = cursor + (size_t)gy * NN;
        int2* eg = ed + (size_t)gy * NE;
        int r0 = rk[dv.x] - 1; if (r0 >= 0) { int p = atomicAdd(&cu[r0], 1); eg[p] = make_int2(sv.x, __float_as_int(wv.x)); }
        int r1 = rk[dv.y] - 1; if (r1 >= 0) { int p = atomicAdd(&cu[r1], 1); eg[p] = make_int2(sv.y, __float_as_int(wv.y)); }
        int r2 = rk[dv.z] - 1; if (r2 >= 0) { int p = atomicAdd(&cu[r2], 1); eg[p] = make_int2(sv.z, __float_as_int(wv.z)); }
        int r3 = rk[dv.w] - 1; if (r3 >= 0) { int p = atomicAdd(&cu[r3], 1); eg[p] = make_int2(sv.w, __float_as_int(wv.w)); }
    }
}

// ---------------------------------------------------------------- fused SAGE conv (layer 1, relu) over compact rows
// 2 rows per wave, interleaved gather groups -> 16 feature-row loads in flight;
// weight float4 loads amortized over both rows.
__global__ __launch_bounds__(256) void k_conv_full(
    const float* __restrict__ emb, const int* __restrict__ row_off,
    const int2* __restrict__ edges,
    const float* __restrict__ Wsf, const float* __restrict__ Wng,
    const float* __restrict__ bias, float* __restrict__ outh,
    const int* __restrict__ list, const int* __restrict__ nlist, int g0)
{
    const int gy = blockIdx.y;
    const int g = g0 + gy;
    const float* feat = emb + (size_t)g * NN * DD;
    const int* ro = row_off + (size_t)gy * (NN + 1);
    const int2* ed = edges + (size_t)gy * NE;
    const int* li = list + (size_t)gy * NN;
    float* og = outh + (size_t)gy * NN * DD;   // compact-row indexed
    const int lane = threadIdx.x & 63;
    const int wid = threadIdx.x >> 6;

    const float bv = bias[(size_t)g * DD + lane];
    const float* wsp = Wsf + (size_t)g * DD * DD + (size_t)lane * DD;
    const float* wnp = Wng + (size_t)g * DD * DD + (size_t)lane * DD;

    __shared__ __attribute__((aligned(16))) float fsA[4][DD];
    __shared__ __attribute__((aligned(16))) float nsA[4][DD];
    __shared__ __attribute__((aligned(16))) float fsB[4][DD];
    __shared__ __attribute__((aligned(16))) float nsB[4][DD];

    const int nl = nlist[gy];
    const int npair = (nl + 1) >> 1;
    const int wglob = blockIdx.x * 4 + wid;
    const int wstep = gridDim.x * 4;
    for (int pr = wglob; pr < npair; pr += wstep) {
        const int tA = 2 * pr;
        const int tB = min(2 * pr + 1, nl - 1);
        const int nA = li[tA], nB = li[tB];
        const int eA0 = ro[tA], eA1 = ro[tA + 1];
        const int eB0 = ro[tB], eB1 = ro[tB + 1];
        const float fsefA = feat[(size_t)nA * DD + lane];
        const float fsefB = feat[(size_t)nB * DD + lane];
        const int cA = eA1 - eA0, cB = eB1 - eB0;
        const int limA = min(cA, 64), limB = min(cB, 64);
        int rSA = 0, rSB = 0; float rWA = 0.f, rWB = 0.f;
        if (lane < limA) { int2 r = ed[eA0 + lane]; rSA = r.x; rWA = __int_as_float(r.y); }
        if (lane < limB) { int2 r = ed[eB0 + lane]; rSB = r.x; rWB = __int_as_float(r.y); }
        float accA = 0.f, accB = 0.f;
        const int lim = max(limA, limB);
        for (int j = 0; j < lim; j += 8) {
            float fvA[8], fvB[8];
            const bool doA = j < limA, doB = j < limB;  // wave-uniform
            if (doA) {
#pragma unroll
                for (int u = 0; u < 8; ++u) {
                    int s = __shfl(rSA, j + u);
                    fvA[u] = feat[(size_t)s * DD + lane];
                }
            }
            if (doB) {
#pragma unroll
                for (int u = 0; u < 8; ++u) {
                    int s = __shfl(rSB, j + u);
                    fvB[u] = feat[(size_t)s * DD + lane];
                }
            }
            if (doA) {
#pragma unroll
                for (int u = 0; u < 8; ++u) accA = fmaf(fvA[u], __shfl(rWA, j + u), accA);
            }
            if (doB) {
#pragma unroll
                for (int u = 0; u < 8; ++u) accB = fmaf(fvB[u], __shfl(rWB, j + u), accB);
            }
        }
        // rare tails (deg > 64)
        for (int bb = eA0 + 64; bb < eA1; bb += 64) {
            int c = min(eA1 - bb, 64);
            int s2 = 0; float w2 = 0.f;
            if (lane < c) { int2 r = ed[bb + lane]; s2 = r.x; w2 = __int_as_float(r.y); }
            for (int u = 0; u < c; ++u)
                accA = fmaf(feat[(size_t)__shfl(s2, u) * DD + lane], __shfl(w2, u), accA);
        }
        for (int bb = eB0 + 64; bb < eB1; bb += 64) {
            int c = min(eB1 - bb, 64);
            int s2 = 0; float w2 = 0.f;
            if (lane < c) { int2 r = ed[bb + lane]; s2 = r.x; w2 = __int_as_float(r.y); }
            for (int u = 0; u < c; ++u)
                accB = fmaf(feat[(size_t)__shfl(s2, u) * DD + lane], __shfl(w2, u), accB);
        }
        const float neighA = accA / fmaxf((float)cA, 1.f);
        const float neighB = accB / fmaxf((float)cB, 1.f);
        fsA[wid][lane] = fsefA; nsA[wid][lane] = neighA;
        fsB[wid][lane] = fsefB; nsB[wid][lane] = neighB;
        float oA = bv, oB = bv;
#pragma unroll
        for (int k4 = 0; k4 < 16; ++k4) {
            float4 ws = *(const float4*)(wsp + 4 * k4);
            float4 wn = *(const float4*)(wnp + 4 * k4);
            float4 fA = *(const float4*)&fsA[wid][4 * k4];
            float4 aA = *(const float4*)&nsA[wid][4 * k4];
            float4 fB = *(const float4*)&fsB[wid][4 * k4];
            float4 aB = *(const float4*)&nsB[wid][4 * k4];
            oA = fmaf(ws.x, fA.x, oA); oA = fmaf(ws.y, fA.y, oA);
            oA = fmaf(ws.z, fA.z, oA); oA = fmaf(ws.w, fA.w, oA);
            oA = fmaf(wn.x, aA.x, oA); oA = fmaf(wn.y, aA.y, oA);
            oA = fmaf(wn.z, aA.z, oA); oA = fmaf(wn.w, aA.w, oA);
            oB = fmaf(ws.x, fB.x, oB); oB = fmaf(ws.y, fB.y, oB);
            oB = fmaf(ws.z, fB.z, oB); oB = fmaf(ws.w, fB.w, oB);
            oB = fmaf(wn.x, aB.x, oB); oB = fmaf(wn.y, aB.y, oB);
            oB = fmaf(wn.z, aB.z, oB); oB = fmaf(wn.w, aB.w, oB);
        }
        og[(size_t)tA * DD + lane] = fmaxf(oA, 0.f);
        og[(size_t)tB * DD + lane] = fmaxf(oB, 0.f);
    }
}

// ---------------------------------------------------------------- fused SAGE conv at candidates (layer 2), h indexed via rank
__global__ __launch_bounds__(256) void k_conv_cand(
    const float* __restrict__ hfeat, const int* __restrict__ row_off,
    const int2* __restrict__ edges, const int* __restrict__ rank,
    const float* __restrict__ Wsf, const float* __restrict__ Wng,
    const float* __restrict__ bias, const int* __restrict__ cand,
    float* __restrict__ sel, int g0)
{
    const int gy = blockIdx.y;
    const int g = g0 + gy;
    const float* feat = hfeat + (size_t)gy * NN * DD;   // compact-row indexed
    const int* ro = row_off + (size_t)gy * (NN + 1);
    const int2* ed = edges + (size_t)gy * NE;
    const int* rk = rank + (size_t)gy * NN;
    const int lane = threadIdx.x & 63;
    const int wid = threadIdx.x >> 6;

    float wsr[DD], wnr[DD];
    {
        const float* wsp = Wsf + (size_t)g * DD * DD + (size_t)lane * DD;
        const float* wnp = Wng + (size_t)g * DD * DD + (size_t)lane * DD;
#pragma unroll
        for (int k4 = 0; k4 < 16; ++k4) {
            float4 a = *(const float4*)(wsp + 4 * k4);
            wsr[4 * k4 + 0] = a.x; wsr[4 * k4 + 1] = a.y; wsr[4 * k4 + 2] = a.z; wsr[4 * k4 + 3] = a.w;
            float4 c = *(const float4*)(wnp + 4 * k4);
            wnr[4 * k4 + 0] = c.x; wnr[4 * k4 + 1] = c.y; wnr[4 * k4 + 2] = c.z; wnr[4 * k4 + 3] = c.w;
        }
    }
    const float bv = bias[(size_t)g * DD + lane];

    __shared__ __attribute__((aligned(16))) float fs[4][DD];
    __shared__ __attribute__((aligned(16))) float nsh[4][DD];

    int t = blockIdx.x * 4 + wid;  // 0..1599
    if (t < NB_ * NL) {
        int b = t / NL;
        int l = t - b * NL;
        int n = cand[((size_t)b * NG + g) * NL + l];
        const int rc = rk[n] - 1;             // candidate is marked
        const int e0 = ro[rc], e1 = ro[rc + 1];
        const float fself = feat[(size_t)rc * DD + lane];
        float acc = 0.f;
        for (int base = e0; base < e1; base += 64) {
            const int cnt = min(e1 - base, 64);
            int   myS = 0;
            float myW = 0.f;
            if (lane < cnt) {
                int2 r = ed[base + lane];
                myS = rk[r.x] - 1;            // sources of candidates are marked
                myW = __int_as_float(r.y);
            }
            for (int j = 0; j < cnt; j += 8) {
                float fv[8], wv[8];
#pragma unroll
                for (int u = 0; u < 8; ++u) {
                    int s = __shfl(myS, j + u);
                    wv[u] = __shfl(myW, j + u);
                    fv[u] = feat[(size_t)max(s, 0) * DD + lane];
                }
#pragma unroll
                for (int u = 0; u < 8; ++u) acc = fmaf(fv[u], wv[u], acc);
            }
        }
        float neigh = acc / fmaxf((float)(e1 - e0), 1.f);
        fs[wid][lane] = fself;
        nsh[wid][lane] = neigh;
        float o = bv;
#pragma unroll
        for (int k4 = 0; k4 < 16; ++k4) {
            float4 f = *(const float4*)&fs[wid][4 * k4];
            float4 nv = *(const float4*)&nsh[wid][4 * k4];
            o = fmaf(wsr[4 * k4 + 0], f.x, o);
            o = fmaf(wsr[4 * k4 + 1], f.y, o);
            o = fmaf(wsr[4 * k4 + 2], f.z, o);
            o = fmaf(wsr[4 * k4 + 3], f.w, o);
            o = fmaf(wnr[4 * k4 + 0], nv.x, o);
            o = fmaf(wnr[4 * k4 + 1], nv.y, o);
            o = fmaf(wnr[4 * k4 + 2], nv.z, o);
            o = fmaf(wnr[4 * k4 + 3], nv.w, o);
        }
        sel[(((size_t)b * NG + g) * NL + l) * DD + lane] = o;  // no relu
    }
}

// ---------------------------------------------------------------- attention stack 1: (B*G) blocks over (L=50, D=64)
__global__ __launch_bounds__(256) void k_attn1(
    const float* __restrict__ sel, const float* __restrict__ Q,
    const float* __restrict__ K, const float* __restrict__ V,
    float* __restrict__ xsum)
{
    __shared__ __attribute__((aligned(16))) float x[NL * DD];
    __shared__ __attribute__((aligned(16))) float qp[NL * 68];
    __shared__ __attribute__((aligned(16))) float kk[NL * 68];
    const int tid = threadIdx.x;
    const int lane = tid & 63;
    const int wid = tid >> 6;
    const int bg = blockIdx.x;
    const float* xin = sel + (size_t)bg * NL * DD;
    for (int i = tid; i < NL * DD; i += 256) x[i] = xin[i];
    __syncthreads();

    for (int layer = 0; layer < NCL; ++layer) {
        const float* Qb = Q + (size_t)layer * DD * DD;
        const float* Kb = K + (size_t)layer * DD * DD;
        const float* Vb = V + (size_t)layer * DD * DD;
        float wrow[DD];
#pragma unroll
        for (int k4 = 0; k4 < 16; ++k4) {
            float4 a = *(const float4*)(Qb + (size_t)lane * DD + 4 * k4);
            wrow[4 * k4 + 0] = a.x; wrow[4 * k4 + 1] = a.y; wrow[4 * k4 + 2] = a.z; wrow[4 * k4 + 3] = a.w;
        }
        for (int l = wid; l < NL; l += 4) {
            float acc = 0.f;
#pragma unroll
            for (int k4 = 0; k4 < 16; ++k4) {
                float4 xv = *(const float4*)&x[l * DD + 4 * k4];
                acc = fmaf(wrow[4 * k4 + 0], xv.x, acc);
                acc = fmaf(wrow[4 * k4 + 1], xv.y, acc);
                acc = fmaf(wrow[4 * k4 + 2], xv.z, acc);
                acc = fmaf(wrow[4 * k4 + 3], xv.w, acc);
            }
            qp[l * 68 + lane] = acc;
        }
#pragma unroll
        for (int k4 = 0; k4 < 16; ++k4) {
            float4 a = *(const float4*)(Kb + (size_t)lane * DD + 4 * k4);
            wrow[4 * k4 + 0] = a.x; wrow[4 * k4 + 1] = a.y; wrow[4 * k4 + 2] = a.z; wrow[4 * k4 + 3] = a.w;
        }
        for (int l = wid; l < NL; l += 4) {
            float acc = 0.f;
#pragma unroll
            for (int k4 = 0; k4 < 16; ++k4) {
                float4 xv = *(const float4*)&x[l * DD + 4 * k4];
                acc = fmaf(wrow[4 * k4 + 0], xv.x, acc);
                acc = fmaf(wrow[4 * k4 + 1], xv.y, acc);
                acc = fmaf(wrow[4 * k4 + 2], xv.z, acc);
                acc = fmaf(wrow[4 * k4 + 3], xv.w, acc);
            }
            kk[l * 68 + lane] = acc;
        }
        __syncthreads();
        for (int l = wid; l < NL; l += 4) {
            float s;
            if (lane < NL) {
                float acc = 0.f;
#pragma unroll
                for (int k4 = 0; k4 < 16; ++k4) {
                    float4 qv = *(const float4*)&qp[l * 68 + 4 * k4];
                    float4 kv = *(const float4*)&kk[lane * 68 + 4 * k4];
                    acc += qv.x * kv.x + qv.y * kv.y + qv.z * kv.z + qv.w * kv.w;
                }
                s = acc * 0.125f;
            } else {
                s = -INFINITY;
            }
            float mx = s;
#pragma unroll
            for (int m = 32; m >= 1; m >>= 1) mx = fmaxf(mx, __shfl_xor(mx, m));
            float pe = __expf(s - mx);
            float sm = pe;
#pragma unroll
            for (int m = 32; m >= 1; m >>= 1) sm += __shfl_xor(sm, m);
            qp[l * 68 + lane] = pe / sm;
        }
        __syncthreads();
        for (int l = wid; l < NL; l += 4) {
            float acc = 0.f;
            for (int m = 0; m < NL; ++m)
                acc = fmaf(qp[l * 68 + m], x[m * DD + lane], acc);
            kk[l * 68 + lane] = acc;
        }
        __syncthreads();
#pragma unroll
        for (int k4 = 0; k4 < 16; ++k4) {
            float4 a = *(const float4*)(Vb + (size_t)lane * DD + 4 * k4);
            wrow[4 * k4 + 0] = a.x; wrow[4 * k4 + 1] = a.y; wrow[4 * k4 + 2] = a.z; wrow[4 * k4 + 3] = a.w;
        }
        for (int l = wid; l < NL; l += 4) {
            float acc = 0.f;
#pragma unroll
            for (int k4 = 0; k4 < 16; ++k4) {
                float4 yv = *(const float4*)&kk[l * 68 + 4 * k4];
                acc = fmaf(wrow[4 * k4 + 0], yv.x, acc);
                acc = fmaf(wrow[4 * k4 + 1], yv.y, acc);
                acc = fmaf(wrow[4 * k4 + 2], yv.z, acc);
                acc = fmaf(wrow[4 * k4 + 3], yv.w, acc);
            }
            x[l * DD + lane] = acc;
        }
        __syncthreads();
    }
    if (wid == 0) {
        float acc = 0.f;
        for (int l = 0; l < NL; ++l) acc += x[l * DD + lane];
        xsum[(size_t)bg * DD + lane] = acc;
    }
}

// ---------------------------------------------------------------- attention stack 2: B blocks over (G=4, D=64)
__global__ __launch_bounds__(64) void k_attn2(
    const float* __restrict__ xin, const float* __restrict__ Q,
    const float* __restrict__ K, const float* __restrict__ V,
    float* __restrict__ out)
{
    __shared__ __attribute__((aligned(16))) float x[NG * DD];
    const int j = threadIdx.x;
    const int b = blockIdx.x;
    for (int i = j; i < NG * DD; i += 64) x[i] = xin[(size_t)b * NG * DD + i];
    __syncthreads();
    float o[NG];
    for (int layer = 0; layer < NCL; ++layer) {
        float wrow[DD];
        float q4[NG], k4v[NG], v4[NG];
        const float* Qb = Q + (size_t)layer * DD * DD + (size_t)j * DD;
        const float* Kb = K + (size_t)layer * DD * DD + (size_t)j * DD;
        const float* Vb = V + (size_t)layer * DD * DD + (size_t)j * DD;
#pragma unroll
        for (int k4 = 0; k4 < 16; ++k4) {
            float4 a = *(const float4*)(Qb + 4 * k4);
            wrow[4 * k4 + 0] = a.x; wrow[4 * k4 + 1] = a.y; wrow[4 * k4 + 2] = a.z; wrow[4 * k4 + 3] = a.w;
        }
#pragma unroll
        for (int g = 0; g < NG; ++g) {
            float acc = 0.f;
#pragma unroll
            for (int k4 = 0; k4 < 16; ++k4) {
                float4 xv = *(const float4*)&x[g * DD + 4 * k4];
                acc = fmaf(wrow[4 * k4 + 0], xv.x, acc);
                acc = fmaf(wrow[4 * k4 + 1], xv.y, acc);
                acc = fmaf(wrow[4 * k4 + 2], xv.z, acc);
                acc = fmaf(wrow[4 * k4 + 3], xv.w, acc);
            }
            q4[g] = acc;
        }
#pragma unroll
        for (int k4 = 0; k4 < 16; ++k4) {
            float4 a = *(const float4*)(Kb + 4 * k4);
            wrow[4 * k4 + 0] = a.x; wrow[4 * k4 + 1] = a.y; wrow[4 * k4 + 2] = a.z; wrow[4 * k4 + 3] = a.w;
        }
#pragma unroll
        for (int g = 0; g < NG; ++g) {
            float acc = 0.f;
#pragma unroll
            for (int k4 = 0; k4 < 16; ++k4) {
                float4 xv = *(const float4*)&x[g * DD + 4 * k4];
                acc = fmaf(wrow[4 * k4 + 0], xv.x, acc);
                acc = fmaf(wrow[4 * k4 + 1], xv.y, acc);
                acc = fmaf(wrow[4 * k4 + 2], xv.z, acc);
                acc = fmaf(wrow[4 * k4 + 3], xv.w, acc);
            }
            k4v[g] = acc;
        }
#pragma unroll
        for (int k4 = 0; k4 < 16; ++k4) {
            float4 a = *(const float4*)(Vb + 4 * k4);
            wrow[4 * k4 + 0] = a.x; wrow[4 * k4 + 1] = a.y; wrow[4 * k4 + 2] = a.z; wrow[4 * k4 + 3] = a.w;
        }
#pragma unroll
        for (int g = 0; g < NG; ++g) {
            float acc = 0.f;
#pragma unroll
            for (int k4 = 0; k4 < 16; ++k4) {
                float4 xv = *(const float4*)&x[g * DD + 4 * k4];
                acc = fmaf(wrow[4 * k4 + 0], xv.x, acc);
                acc = fmaf(wrow[4 * k4 + 1], xv.y, acc);
                acc = fmaf(wrow[4 * k4 + 2], xv.z, acc);
                acc = fmaf(wrow[4 * k4 + 3], xv.w, acc);
            }
            v4[g] = acc;
        }
        float p[NG][NG];
#pragma unroll
        for (int l = 0; l < NG; ++l) {
#pragma unroll
            for (int m = 0; m < NG; ++m) {
                float t = q4[l] * k4v[m];
#pragma unroll
                for (int mk = 32; mk >= 1; mk >>= 1) t += __shfl_xor(t, mk);
                p[l][m] = t * 0.125f;
            }
        }
#pragma unroll
        for (int l = 0; l < NG; ++l) {
            float mx = fmaxf(fmaxf(p[l][0], p[l][1]), fmaxf(p[l][2], p[l][3]));
            float e0 = __expf(p[l][0] - mx), e1 = __expf(p[l][1] - mx);
            float e2 = __expf(p[l][2] - mx), e3 = __expf(p[l][3] - mx);
            float inv = 1.f / (e0 + e1 + e2 + e3);
            o[l] = (e0 * v4[0] + e1 * v4[1] + e2 * v4[2] + e3 * v4[3]) * inv;
        }
        __syncthreads();
#pragma unroll
        for (int l = 0; l < NG; ++l) x[l * DD + j] = o[l];
        __syncthreads();
    }
    out[(size_t)b * DD + j] = o[0] + o[1] + o[2] + o[3];
}

// ---------------------------------------------------------------- host
extern "C" void kernel_launch(void* const* d_in, const int* in_sizes, int n_in,
                              void* d_out, int out_size, void* d_ws, size_t ws_size,
                              hipStream_t stream)
{
    const int*   src  = (const int*)  d_in[0];
    const int*   dst  = (const int*)  d_in[1];
    const float* ew   = (const float*)d_in[2];
    const float* emb  = (const float*)d_in[3];
    const float* Ws1  = (const float*)d_in[4];
    const float* Wn1  = (const float*)d_in[5];
    const float* b1   = (const float*)d_in[6];
    const float* Ws2  = (const float*)d_in[7];
    const float* Wn2  = (const float*)d_in[8];
    const float* b2   = (const float*)d_in[9];
    const float* Q1   = (const float*)d_in[10];
    const float* K1   = (const float*)d_in[11];
    const float* V1   = (const float*)d_in[12];
    const float* Q2   = (const float*)d_in[13];
    const float* K2   = (const float*)d_in[14];
    const float* V2   = (const float*)d_in[15];
    const int*   cand = (const int*)  d_in[16];
    float* out = (float*)d_out;

    auto padded = [](size_t b) { return (b + 255) & ~(size_t)255; };
    auto need = [&](int GG) -> size_t {
        size_t s = 0;
        s += padded((size_t)GG * (NN + 1) * 4);   // cnt
        s += padded((size_t)GG * 64 * 4);         // part
        s += padded((size_t)GG * (NN + 1) * 4);   // row_off
        s += padded((size_t)GG * NN * 4);         // cursor
        s += padded((size_t)GG * NE * 8);         // packed edges
        s += padded((size_t)GG * NN * DD * 4);    // h (compact rows)
        s += padded((size_t)NB_ * NG * NL * DD * 4); // sel
        s += padded((size_t)NB_ * NG * DD * 4);      // xsum
        s += padded((size_t)GG * NN * 4);         // candbm
        s += padded((size_t)GG * NN * 4);         // mark
        s += padded((size_t)GG * 64 * 4);         // partc
        s += padded((size_t)GG * NN * 4);         // list
        s += padded((size_t)GG * NN * 4);         // rank
        s += padded((size_t)GG * 64 * 4);         // nlist
        return s;
    };
    const int GG = (ws_size >= need(4)) ? 4 : 1;

    char* p = (char*)d_ws;
    auto alloc = [&](size_t b) -> void* { void* r = (void*)p; p += padded(b); return r; };
    int*   cnt  = (int*)  alloc((size_t)GG * (NN + 1) * 4);
    int*   part = (int*)  alloc((size_t)GG * 64 * 4);
    int*   roff = (int*)  alloc((size_t)GG * (NN + 1) * 4);
    int*   cur  = (int*)  alloc((size_t)GG * NN * 4);
    int2*  edg  = (int2*) alloc((size_t)GG * NE * 8);
    float* hb   = (float*)alloc((size_t)GG * NN * DD * 4);
    float* sel  = (float*)alloc((size_t)NB_ * NG * NL * DD * 4);
    float* xsum = (float*)alloc((size_t)NB_ * NG * DD * 4);
    int*   cbm  = (int*)  alloc((size_t)GG * NN * 4);
    int*   mark = (int*)  alloc((size_t)GG * NN * 4);
    int*   prtc = (int*)  alloc((size_t)GG * 64 * 4);
    int*   list = (int*)  alloc((size_t)GG * NN * 4);
    int*   rank = (int*)  alloc((size_t)GG * NN * 4);
    int*   nlst = (int*)  alloc((size_t)GG * 64 * 4);

    const int QB = (NE / 4 + 255) / 256;  // 4-edge-per-thread blocks
    const int CB = (NB_ * NL + 255) / 256;
    for (int g0 = 0; g0 < NG; g0 += GG) {
        hipMemsetAsync(cnt, 0, (size_t)GG * (NN + 1) * 4, stream);
        hipMemsetAsync(cbm, 0, (size_t)GG * NN * 4, stream);
        hipMemsetAsync(mark, 0, (size_t)GG * NN * 4, stream);
        k_candmark<<<dim3(CB, GG), 256, 0, stream>>>(cand, cbm, mark, g0);
        k_mark2   <<<dim3(QB, GG), 256, 0, stream>>>(src, dst, cbm, mark, g0);
        k_cscan1  <<<dim3(SCAN_NB, GG), 256, 0, stream>>>(mark, prtc);
        k_cscan3  <<<dim3(SCAN_NB, GG), 256, 0, stream>>>(mark, prtc, list, rank, nlst);
        k_hist2   <<<dim3(QB, GG), 256, 0, stream>>>(dst, rank, cnt, g0);
        k_scan1   <<<dim3(SCAN_NB, GG), 256, 0, stream>>>(cnt, part);
        k_scan3   <<<dim3(SCAN_NB, GG), 256, 0, stream>>>(cnt, part, roff, cur);
        k_scatter2<<<dim3(QB, GG), 256, 0, stream>>>(src, dst, ew, rank, cur, edg, g0);
        k_conv_full<<<dim3(320, GG), 256, 0, stream>>>(emb, roff, edg, Ws1, Wn1, b1, hb, list, nlst, g0);
        k_conv_cand<<<dim3((NB_ * NL) / 4, GG), 256, 0, stream>>>(hb, roff, edg, rank, Ws2, Wn2, b2, cand, sel, g0);
    }
    k_attn1<<<NB_ * NG, 256, 0, stream>>>(sel, Q1, K1, V1, xsum);
    k_attn2<<<NB_, 64, 0, stream>>>(xsum, Q2, K2, V2, out);
}

// Round 7
// 402.486 us; speedup vs baseline: 17.7987x; 1.2258x over previous
//
#include <hip/hip_runtime.h>
#include <cstdint>
#include <cstddef>
#include <cmath>

#define NN   100000   // nodes per graph
#define NE   1600000  // edges per graph
#define DD   64       // feature dim
#define NG   4        // graphs
#define NB_  32       // batch
#define NL   50       // candidate list length
#define NCL  2        // attention layers per stack
#define SCAN_NB 49    // ceil(NN/2048)

// ---------------------------------------------------------------- mark candidates
__global__ __launch_bounds__(256) void k_candmark(const int* __restrict__ cand,
                                                  int* __restrict__ candbm,
                                                  int* __restrict__ mark, int g0) {
    const int gy = blockIdx.y;
    const int g = g0 + gy;
    int t = blockIdx.x * 256 + threadIdx.x;
    if (t < NB_ * NL) {
        int b = t / NL, l = t - b * NL;
        int n = cand[((size_t)b * NG + g) * NL + l];
        candbm[(size_t)gy * NN + n] = 1;
        mark[(size_t)gy * NN + n] = 1;
    }
}

// stream edges once: mark sources of candidate in-edges AND count per-dst degree
// (histogram fused in; cnt is node-indexed, zero for non-candidates)
__global__ __launch_bounds__(256) void k_mark2(const int* __restrict__ src,
                                               const int* __restrict__ dst,
                                               const int* __restrict__ candbm,
                                               int* __restrict__ mark,
                                               int* __restrict__ cnt, int g0) {
    const int gy = blockIdx.y;
    const int g = g0 + gy;
    int q = blockIdx.x * 256 + threadIdx.x;
    if (q < NE / 4) {
        int4 dv = ((const int4*)(dst + (size_t)g * NE))[q];
        int4 sv = ((const int4*)(src + (size_t)g * NE))[q];
        const int* cb = candbm + (size_t)gy * NN;
        int* mk = mark + (size_t)gy * NN;
        int* c = cnt + (size_t)gy * (NN + 1);
        if (cb[dv.x]) { mk[sv.x] = 1; atomicAdd(&c[dv.x], 1); }
        if (cb[dv.y]) { mk[sv.y] = 1; atomicAdd(&c[dv.y], 1); }
        if (cb[dv.z]) { mk[sv.z] = 1; atomicAdd(&c[dv.z], 1); }
        if (cb[dv.w]) { mk[sv.w] = 1; atomicAdd(&c[dv.w], 1); }
    }
}

// ---------------------------------------------------------------- compact marked -> list + rank
__global__ __launch_bounds__(256) void k_cscan1(const int* __restrict__ mark,
                                                int* __restrict__ partc) {
    const int gy = blockIdx.y;
    const int* m = mark + (size_t)gy * NN;
    __shared__ int sh[256];
    const int tid = threadIdx.x;
    int base = blockIdx.x * 2048 + tid * 8;
    int s = 0;
    for (int i = 0; i < 8; ++i) { int idx = base + i; if (idx < NN) s += m[idx]; }
    sh[tid] = s; __syncthreads();
    for (int off = 128; off > 0; off >>= 1) {
        if (tid < off) sh[tid] += sh[tid + off];
        __syncthreads();
    }
    if (tid == 0) partc[gy * 64 + blockIdx.x] = sh[0];
}

// fused: per-block serial prefix of raw partials; last block writes nlist
__global__ __launch_bounds__(256) void k_cscan3(const int* __restrict__ mark,
                                                const int* __restrict__ partc,
                                                int* __restrict__ list,
                                                int* __restrict__ rank,
                                                int* __restrict__ nlist) {
    const int gy = blockIdx.y;
    const int* m = mark + (size_t)gy * NN;
    int* li = list + (size_t)gy * NN;
    int* rk = rank + (size_t)gy * NN;
    __shared__ int sh[256];
    __shared__ int sbase;
    const int tid = threadIdx.x;
    if (tid == 0) {
        int b = 0;
        for (int i = 0; i < blockIdx.x; ++i) b += partc[gy * 64 + i];
        sbase = b;
    }
    int base = blockIdx.x * 2048 + tid * 8;
    int vals[8];
    int s = 0;
    for (int i = 0; i < 8; ++i) {
        int idx = base + i;
        int v = (idx < NN) ? m[idx] : 0;
        vals[i] = v; s += v;
    }
    sh[tid] = s; __syncthreads();
    for (int off = 1; off < 256; off <<= 1) {
        int t = (tid >= off) ? sh[tid - off] : 0;
        __syncthreads();
        sh[tid] += t;
        __syncthreads();
    }
    int excl = sh[tid] - s;
    int run = sbase + excl;
    for (int i = 0; i < 8; ++i) {
        int idx = base + i;
        if (idx < NN) {
            if (vals[i]) { li[run] = idx; rk[idx] = run + 1; ++run; }
            else rk[idx] = 0;
        }
    }
    if (blockIdx.x == SCAN_NB - 1 && tid == 255) nlist[gy] = sbase + sh[255];
}

// ---------------------------------------------------------------- node-indexed CSR offsets
__global__ __launch_bounds__(256) void k_scan1(const int* __restrict__ cnt,
                                               int* __restrict__ part) {
    const int gy = blockIdx.y;
    const int* c = cnt + (size_t)gy * (NN + 1);
    __shared__ int sh[256];
    const int tid = threadIdx.x;
    int base = blockIdx.x * 2048 + tid * 8;
    int s = 0;
    for (int i = 0; i < 8; ++i) { int idx = base + i; if (idx < NN) s += c[idx]; }
    sh[tid] = s; __syncthreads();
    for (int off = 128; off > 0; off >>= 1) {
        if (tid < off) sh[tid] += sh[tid + off];
        __syncthreads();
    }
    if (tid == 0) part[gy * 64 + blockIdx.x] = sh[0];
}

// fused: per-block serial prefix of raw partials; writes node-indexed ro + cursor
__global__ __launch_bounds__(256) void k_scan3(const int* __restrict__ cnt,
                                               const int* __restrict__ part,
                                               int* __restrict__ row_off,
                                               int* __restrict__ cursor) {
    const int gy = blockIdx.y;
    const int* c = cnt + (size_t)gy * (NN + 1);
    int* ro = row_off + (size_t)gy * (NN + 1);
    int* cu = cursor + (size_t)gy * NN;
    __shared__ int sh[256];
    __shared__ int sbase;
    const int tid = threadIdx.x;
    if (tid == 0) {
        int b = 0;
        for (int i = 0; i < blockIdx.x; ++i) b += part[gy * 64 + i];
        sbase = b;
    }
    int base = blockIdx.x * 2048 + tid * 8;
    int vals[8];
    int s = 0;
    for (int i = 0; i < 8; ++i) {
        int idx = base + i;
        int v = (idx < NN) ? c[idx] : 0;
        vals[i] = v; s += v;
    }
    sh[tid] = s; __syncthreads();
    for (int off = 1; off < 256; off <<= 1) {
        int t = (tid >= off) ? sh[tid - off] : 0;
        __syncthreads();
        sh[tid] += t;
        __syncthreads();
    }
    int excl = sh[tid] - s;
    int run = sbase + excl;
    for (int i = 0; i < 8; ++i) {
        int idx = base + i;
        if (idx < NN) { ro[idx] = run; cu[idx] = run; run += vals[i]; }
    }
    if (blockIdx.x == SCAN_NB - 1 && tid == 255) ro[NN] = sbase + sh[255];
}

// scatter only edges whose dst is a candidate (node-indexed cursor, no rank lookup)
__global__ __launch_bounds__(256) void k_scatter2(const int* __restrict__ src,
                                                  const int* __restrict__ dst,
                                                  const float* __restrict__ ew,
                                                  const int* __restrict__ candbm,
                                                  int* __restrict__ cursor,
                                                  int2* __restrict__ ed, int g0) {
    const int gy = blockIdx.y;
    const int g = g0 + gy;
    int q = blockIdx.x * 256 + threadIdx.x;
    if (q < NE / 4) {
        int4   dv = ((const int4*)(dst + (size_t)g * NE))[q];
        int4   sv = ((const int4*)(src + (size_t)g * NE))[q];
        float4 wv = ((const float4*)(ew + (size_t)g * NE))[q];
        const int* cb = candbm + (size_t)gy * NN;
        int* cu = cursor + (size_t)gy * NN;
        int2* eg = ed + (size_t)gy * NE;
        if (cb[dv.x]) { int p = atomicAdd(&cu[dv.x], 1); eg[p] = make_int2(sv.x, __float_as_int(wv.x)); }
        if (cb[dv.y]) { int p = atomicAdd(&cu[dv.y], 1); eg[p] = make_int2(sv.y, __float_as_int(wv.y)); }
        if (cb[dv.z]) { int p = atomicAdd(&cu[dv.z], 1); eg[p] = make_int2(sv.z, __float_as_int(wv.z)); }
        if (cb[dv.w]) { int p = atomicAdd(&cu[dv.w], 1); eg[p] = make_int2(sv.w, __float_as_int(wv.w)); }
    }
}

// ---------------------------------------------------------------- fused SAGE conv (layer 1, relu) over marked nodes
// single-row body (88 VGPR, 5 waves/SIMD); huge grid -> ~1 row per wave
__global__ __launch_bounds__(256) void k_conv_full(
    const float* __restrict__ emb, const int* __restrict__ row_off,
    const int2* __restrict__ edges,
    const float* __restrict__ Wsf, const float* __restrict__ Wng,
    const float* __restrict__ bias, float* __restrict__ outh,
    const int* __restrict__ list, const int* __restrict__ nlist, int g0)
{
    const int gy = blockIdx.y;
    const int g = g0 + gy;
    const float* feat = emb + (size_t)g * NN * DD;
    const int* ro = row_off + (size_t)gy * (NN + 1);
    const int2* ed = edges + (size_t)gy * NE;
    const int* li = list + (size_t)gy * NN;
    float* og = outh + (size_t)gy * NN * DD;   // compact-row indexed
    const int lane = threadIdx.x & 63;
    const int wid = threadIdx.x >> 6;

    float wsr[DD], wnr[DD];
    {
        const float* wsp = Wsf + (size_t)g * DD * DD + (size_t)lane * DD;
        const float* wnp = Wng + (size_t)g * DD * DD + (size_t)lane * DD;
#pragma unroll
        for (int k4 = 0; k4 < 16; ++k4) {
            float4 a = *(const float4*)(wsp + 4 * k4);
            wsr[4 * k4 + 0] = a.x; wsr[4 * k4 + 1] = a.y; wsr[4 * k4 + 2] = a.z; wsr[4 * k4 + 3] = a.w;
            float4 c = *(const float4*)(wnp + 4 * k4);
            wnr[4 * k4 + 0] = c.x; wnr[4 * k4 + 1] = c.y; wnr[4 * k4 + 2] = c.z; wnr[4 * k4 + 3] = c.w;
        }
    }
    const float bv = bias[(size_t)g * DD + lane];

    __shared__ __attribute__((aligned(16))) float fs[4][DD];
    __shared__ __attribute__((aligned(16))) float ns[4][DD];

    const int nl = nlist[gy];
    const int wglob = blockIdx.x * 4 + wid;
    const int wstep = gridDim.x * 4;
    for (int t = wglob; t < nl; t += wstep) {
        const int n = li[t];
        const int e0 = ro[n], e1 = ro[n + 1];
        const float fself = feat[(size_t)n * DD + lane];
        float acc = 0.f;
        for (int base = e0; base < e1; base += 64) {
            const int cnt = min(e1 - base, 64);
            int   myS = 0;
            float myW = 0.f;
            if (lane < cnt) {
                int2 r = ed[base + lane];
                myS = r.x; myW = __int_as_float(r.y);
            }
            for (int j = 0; j < cnt; j += 8) {
                float fv[8], wv[8];
#pragma unroll
                for (int u = 0; u < 8; ++u) {
                    int s = __shfl(myS, j + u);
                    wv[u] = __shfl(myW, j + u);
                    fv[u] = feat[(size_t)s * DD + lane];
                }
#pragma unroll
                for (int u = 0; u < 8; ++u) acc = fmaf(fv[u], wv[u], acc);
            }
        }
        float neigh = acc / fmaxf((float)(e1 - e0), 1.f);
        fs[wid][lane] = fself;
        ns[wid][lane] = neigh;
        float o = bv;
#pragma unroll
        for (int k4 = 0; k4 < 16; ++k4) {
            float4 f = *(const float4*)&fs[wid][4 * k4];
            float4 nv = *(const float4*)&ns[wid][4 * k4];
            o = fmaf(wsr[4 * k4 + 0], f.x, o);
            o = fmaf(wsr[4 * k4 + 1], f.y, o);
            o = fmaf(wsr[4 * k4 + 2], f.z, o);
            o = fmaf(wsr[4 * k4 + 3], f.w, o);
            o = fmaf(wnr[4 * k4 + 0], nv.x, o);
            o = fmaf(wnr[4 * k4 + 1], nv.y, o);
            o = fmaf(wnr[4 * k4 + 2], nv.z, o);
            o = fmaf(wnr[4 * k4 + 3], nv.w, o);
        }
        o = fmaxf(o, 0.f);  // relu
        og[(size_t)t * DD + lane] = o;
    }
}

// ---------------------------------------------------------------- fused SAGE conv at candidates (layer 2), h indexed via rank
__global__ __launch_bounds__(256) void k_conv_cand(
    const float* __restrict__ hfeat, const int* __restrict__ row_off,
    const int2* __restrict__ edges, const int* __restrict__ rank,
    const float* __restrict__ Wsf, const float* __restrict__ Wng,
    const float* __restrict__ bias, const int* __restrict__ cand,
    float* __restrict__ sel, int g0)
{
    const int gy = blockIdx.y;
    const int g = g0 + gy;
    const float* feat = hfeat + (size_t)gy * NN * DD;   // compact-row indexed
    const int* ro = row_off + (size_t)gy * (NN + 1);    // node-indexed
    const int2* ed = edges + (size_t)gy * NE;
    const int* rk = rank + (size_t)gy * NN;
    const int lane = threadIdx.x & 63;
    const int wid = threadIdx.x >> 6;

    float wsr[DD], wnr[DD];
    {
        const float* wsp = Wsf + (size_t)g * DD * DD + (size_t)lane * DD;
        const float* wnp = Wng + (size_t)g * DD * DD + (size_t)lane * DD;
#pragma unroll
        for (int k4 = 0; k4 < 16; ++k4) {
            float4 a = *(const float4*)(wsp + 4 * k4);
            wsr[4 * k4 + 0] = a.x; wsr[4 * k4 + 1] = a.y; wsr[4 * k4 + 2] = a.z; wsr[4 * k4 + 3] = a.w;
            float4 c = *(const float4*)(wnp + 4 * k4);
            wnr[4 * k4 + 0] = c.x; wnr[4 * k4 + 1] = c.y; wnr[4 * k4 + 2] = c.z; wnr[4 * k4 + 3] = c.w;
        }
    }
    const float bv = bias[(size_t)g * DD + lane];

    __shared__ __attribute__((aligned(16))) float fs[4][DD];
    __shared__ __attribute__((aligned(16))) float nsh[4][DD];

    int t = blockIdx.x * 4 + wid;  // 0..1599
    if (t < NB_ * NL) {
        int b = t / NL;
        int l = t - b * NL;
        int n = cand[((size_t)b * NG + g) * NL + l];
        const int rc = rk[n] - 1;             // candidate is marked
        const int e0 = ro[n], e1 = ro[n + 1];
        const float fself = feat[(size_t)rc * DD + lane];
        float acc = 0.f;
        for (int base = e0; base < e1; base += 64) {
            const int cnt = min(e1 - base, 64);
            int   myS = 0;
            float myW = 0.f;
            if (lane < cnt) {
                int2 r = ed[base + lane];
                myS = rk[r.x] - 1;            // sources of candidates are marked
                myW = __int_as_float(r.y);
            }
            for (int j = 0; j < cnt; j += 8) {
                float fv[8], wv[8];
#pragma unroll
                for (int u = 0; u < 8; ++u) {
                    int s = __shfl(myS, j + u);
                    wv[u] = __shfl(myW, j + u);
                    fv[u] = feat[(size_t)max(s, 0) * DD + lane];
                }
#pragma unroll
                for (int u = 0; u < 8; ++u) acc = fmaf(fv[u], wv[u], acc);
            }
        }
        float neigh = acc / fmaxf((float)(e1 - e0), 1.f);
        fs[wid][lane] = fself;
        nsh[wid][lane] = neigh;
        float o = bv;
#pragma unroll
        for (int k4 = 0; k4 < 16; ++k4) {
            float4 f = *(const float4*)&fs[wid][4 * k4];
            float4 nv = *(const float4*)&nsh[wid][4 * k4];
            o = fmaf(wsr[4 * k4 + 0], f.x, o);
            o = fmaf(wsr[4 * k4 + 1], f.y, o);
            o = fmaf(wsr[4 * k4 + 2], f.z, o);
            o = fmaf(wsr[4 * k4 + 3], f.w, o);
            o = fmaf(wnr[4 * k4 + 0], nv.x, o);
            o = fmaf(wnr[4 * k4 + 1], nv.y, o);
            o = fmaf(wnr[4 * k4 + 2], nv.z, o);
            o = fmaf(wnr[4 * k4 + 3], nv.w, o);
        }
        sel[(((size_t)b * NG + g) * NL + l) * DD + lane] = o;  // no relu
    }
}

// ---------------------------------------------------------------- attention stack 1: (B*G) blocks over (L=50, D=64)
__global__ __launch_bounds__(256) void k_attn1(
    const float* __restrict__ sel, const float* __restrict__ Q,
    const float* __restrict__ K, const float* __restrict__ V,
    float* __restrict__ xsum)
{
    __shared__ __attribute__((aligned(16))) float x[NL * DD];
    __shared__ __attribute__((aligned(16))) float qp[NL * 68];
    __shared__ __attribute__((aligned(16))) float kk[NL * 68];
    const int tid = threadIdx.x;
    const int lane = tid & 63;
    const int wid = tid >> 6;
    const int bg = blockIdx.x;
    const float* xin = sel + (size_t)bg * NL * DD;
    for (int i = tid; i < NL * DD; i += 256) x[i] = xin[i];
    __syncthreads();

    for (int layer = 0; layer < NCL; ++layer) {
        const float* Qb = Q + (size_t)layer * DD * DD;
        const float* Kb = K + (size_t)layer * DD * DD;
        const float* Vb = V + (size_t)layer * DD * DD;
        float wrow[DD];
#pragma unroll
        for (int k4 = 0; k4 < 16; ++k4) {
            float4 a = *(const float4*)(Qb + (size_t)lane * DD + 4 * k4);
            wrow[4 * k4 + 0] = a.x; wrow[4 * k4 + 1] = a.y; wrow[4 * k4 + 2] = a.z; wrow[4 * k4 + 3] = a.w;
        }
        for (int l = wid; l < NL; l += 4) {
            float acc = 0.f;
#pragma unroll
            for (int k4 = 0; k4 < 16; ++k4) {
                float4 xv = *(const float4*)&x[l * DD + 4 * k4];
                acc = fmaf(wrow[4 * k4 + 0], xv.x, acc);
                acc = fmaf(wrow[4 * k4 + 1], xv.y, acc);
                acc = fmaf(wrow[4 * k4 + 2], xv.z, acc);
                acc = fmaf(wrow[4 * k4 + 3], xv.w, acc);
            }
            qp[l * 68 + lane] = acc;
        }
#pragma unroll
        for (int k4 = 0; k4 < 16; ++k4) {
            float4 a = *(const float4*)(Kb + (size_t)lane * DD + 4 * k4);
            wrow[4 * k4 + 0] = a.x; wrow[4 * k4 + 1] = a.y; wrow[4 * k4 + 2] = a.z; wrow[4 * k4 + 3] = a.w;
        }
        for (int l = wid; l < NL; l += 4) {
            float acc = 0.f;
#pragma unroll
            for (int k4 = 0; k4 < 16; ++k4) {
                float4 xv = *(const float4*)&x[l * DD + 4 * k4];
                acc = fmaf(wrow[4 * k4 + 0], xv.x, acc);
                acc = fmaf(wrow[4 * k4 + 1], xv.y, acc);
                acc = fmaf(wrow[4 * k4 + 2], xv.z, acc);
                acc = fmaf(wrow[4 * k4 + 3], xv.w, acc);
            }
            kk[l * 68 + lane] = acc;
        }
        __syncthreads();
        for (int l = wid; l < NL; l += 4) {
            float s;
            if (lane < NL) {
                float acc = 0.f;
#pragma unroll
                for (int k4 = 0; k4 < 16; ++k4) {
                    float4 qv = *(const float4*)&qp[l * 68 + 4 * k4];
                    float4 kv = *(const float4*)&kk[lane * 68 + 4 * k4];
                    acc += qv.x * kv.x + qv.y * kv.y + qv.z * kv.z + qv.w * kv.w;
                }
                s = acc * 0.125f;
            } else {
                s = -INFINITY;
            }
            float mx = s;
#pragma unroll
            for (int m = 32; m >= 1; m >>= 1) mx = fmaxf(mx, __shfl_xor(mx, m));
            float pe = __expf(s - mx);
            float sm = pe;
#pragma unroll
            for (int m = 32; m >= 1; m >>= 1) sm += __shfl_xor(sm, m);
            qp[l * 68 + lane] = pe / sm;
        }
        __syncthreads();
        for (int l = wid; l < NL; l += 4) {
            float acc = 0.f;
            for (int m = 0; m < NL; ++m)
                acc = fmaf(qp[l * 68 + m], x[m * DD + lane], acc);
            kk[l * 68 + lane] = acc;
        }
        __syncthreads();
#pragma unroll
        for (int k4 = 0; k4 < 16; ++k4) {
            float4 a = *(const float4*)(Vb + (size_t)lane * DD + 4 * k4);
            wrow[4 * k4 + 0] = a.x; wrow[4 * k4 + 1] = a.y; wrow[4 * k4 + 2] = a.z; wrow[4 * k4 + 3] = a.w;
        }
        for (int l = wid; l < NL; l += 4) {
            float acc = 0.f;
#pragma unroll
            for (int k4 = 0; k4 < 16; ++k4) {
                float4 yv = *(const float4*)&kk[l * 68 + 4 * k4];
                acc = fmaf(wrow[4 * k4 + 0], yv.x, acc);
                acc = fmaf(wrow[4 * k4 + 1], yv.y, acc);
                acc = fmaf(wrow[4 * k4 + 2], yv.z, acc);
                acc = fmaf(wrow[4 * k4 + 3], yv.w, acc);
            }
            x[l * DD + lane] = acc;
        }
        __syncthreads();
    }
    if (wid == 0) {
        float acc = 0.f;
        for (int l = 0; l < NL; ++l) acc += x[l * DD + lane];
        xsum[(size_t)bg * DD + lane] = acc;
    }
}

// ---------------------------------------------------------------- attention stack 2: B blocks over (G=4, D=64)
__global__ __launch_bounds__(64) void k_attn2(
    const float* __restrict__ xin, const float* __restrict__ Q,
    const float* __restrict__ K, const float* __restrict__ V,
    float* __restrict__ out)
{
    __shared__ __attribute__((aligned(16))) float x[NG * DD];
    const int j = threadIdx.x;
    const int b = blockIdx.x;
    for (int i = j; i < NG * DD; i += 64) x[i] = xin[(size_t)b * NG * DD + i];
    __syncthreads();
    float o[NG];
    for (int layer = 0; layer < NCL; ++layer) {
        float wrow[DD];
        float q4[NG], k4v[NG], v4[NG];
        const float* Qb = Q + (size_t)layer * DD * DD + (size_t)j * DD;
        const float* Kb = K + (size_t)layer * DD * DD + (size_t)j * DD;
        const float* Vb = V + (size_t)layer * DD * DD + (size_t)j * DD;
#pragma unroll
        for (int k4 = 0; k4 < 16; ++k4) {
            float4 a = *(const float4*)(Qb + 4 * k4);
            wrow[4 * k4 + 0] = a.x; wrow[4 * k4 + 1] = a.y; wrow[4 * k4 + 2] = a.z; wrow[4 * k4 + 3] = a.w;
        }
#pragma unroll
        for (int g = 0; g < NG; ++g) {
            float acc = 0.f;
#pragma unroll
            for (int k4 = 0; k4 < 16; ++k4) {
                float4 xv = *(const float4*)&x[g * DD + 4 * k4];
                acc = fmaf(wrow[4 * k4 + 0], xv.x, acc);
                acc = fmaf(wrow[4 * k4 + 1], xv.y, acc);
                acc = fmaf(wrow[4 * k4 + 2], xv.z, acc);
                acc = fmaf(wrow[4 * k4 + 3], xv.w, acc);
            }
            q4[g] = acc;
        }
#pragma unroll
        for (int k4 = 0; k4 < 16; ++k4) {
            float4 a = *(const float4*)(Kb + 4 * k4);
            wrow[4 * k4 + 0] = a.x; wrow[4 * k4 + 1] = a.y; wrow[4 * k4 + 2] = a.z; wrow[4 * k4 + 3] = a.w;
        }
#pragma unroll
        for (int g = 0; g < NG; ++g) {
            float acc = 0.f;
#pragma unroll
            for (int k4 = 0; k4 < 16; ++k4) {
                float4 xv = *(const float4*)&x[g * DD + 4 * k4];
                acc = fmaf(wrow[4 * k4 + 0], xv.x, acc);
                acc = fmaf(wrow[4 * k4 + 1], xv.y, acc);
                acc = fmaf(wrow[4 * k4 + 2], xv.z, acc);
                acc = fmaf(wrow[4 * k4 + 3], xv.w, acc);
            }
            k4v[g] = acc;
        }
#pragma unroll
        for (int k4 = 0; k4 < 16; ++k4) {
            float4 a = *(const float4*)(Vb + 4 * k4);
            wrow[4 * k4 + 0] = a.x; wrow[4 * k4 + 1] = a.y; wrow[4 * k4 + 2] = a.z; wrow[4 * k4 + 3] = a.w;
        }
#pragma unroll
        for (int g = 0; g < NG; ++g) {
            float acc = 0.f;
#pragma unroll
            for (int k4 = 0; k4 < 16; ++k4) {
                float4 xv = *(const float4*)&x[g * DD + 4 * k4];
                acc = fmaf(wrow[4 * k4 + 0], xv.x, acc);
                acc = fmaf(wrow[4 * k4 + 1], xv.y, acc);
                acc = fmaf(wrow[4 * k4 + 2], xv.z, acc);
                acc = fmaf(wrow[4 * k4 + 3], xv.w, acc);
            }
            v4[g] = acc;
        }
        float p[NG][NG];
#pragma unroll
        for (int l = 0; l < NG; ++l) {
#pragma unroll
            for (int m = 0; m < NG; ++m) {
                float t = q4[l] * k4v[m];
#pragma unroll
                for (int mk = 32; mk >= 1; mk >>= 1) t += __shfl_xor(t, mk);
                p[l][m] = t * 0.125f;
            }
        }
#pragma unroll
        for (int l = 0; l < NG; ++l) {
            float mx = fmaxf(fmaxf(p[l][0], p[l][1]), fmaxf(p[l][2], p[l][3]));
            float e0 = __expf(p[l][0] - mx), e1 = __expf(p[l][1] - mx);
            float e2 = __expf(p[l][2] - mx), e3 = __expf(p[l][3] - mx);
            float inv = 1.f / (e0 + e1 + e2 + e3);
            o[l] = (e0 * v4[0] + e1 * v4[1] + e2 * v4[2] + e3 * v4[3]) * inv;
        }
        __syncthreads();
#pragma unroll
        for (int l = 0; l < NG; ++l) x[l * DD + j] = o[l];
        __syncthreads();
    }
    out[(size_t)b * DD + j] = o[0] + o[1] + o[2] + o[3];
}

// ---------------------------------------------------------------- host
extern "C" void kernel_launch(void* const* d_in, const int* in_sizes, int n_in,
                              void* d_out, int out_size, void* d_ws, size_t ws_size,
                              hipStream_t stream)
{
    const int*   src  = (const int*)  d_in[0];
    const int*   dst  = (const int*)  d_in[1];
    const float* ew   = (const float*)d_in[2];
    const float* emb  = (const float*)d_in[3];
    const float* Ws1  = (const float*)d_in[4];
    const float* Wn1  = (const float*)d_in[5];
    const float* b1   = (const float*)d_in[6];
    const float* Ws2  = (const float*)d_in[7];
    const float* Wn2  = (const float*)d_in[8];
    const float* b2   = (const float*)d_in[9];
    const float* Q1   = (const float*)d_in[10];
    const float* K1   = (const float*)d_in[11];
    const float* V1   = (const float*)d_in[12];
    const float* Q2   = (const float*)d_in[13];
    const float* K2   = (const float*)d_in[14];
    const float* V2   = (const float*)d_in[15];
    const int*   cand = (const int*)  d_in[16];
    float* out = (float*)d_out;

    auto padded = [](size_t b) { return (b + 255) & ~(size_t)255; };
    auto need = [&](int GG) -> size_t {
        size_t s = 0;
        s += padded((size_t)GG * (NN + 1) * 4);   // cnt
        s += padded((size_t)GG * 64 * 4);         // part
        s += padded((size_t)GG * (NN + 1) * 4);   // row_off
        s += padded((size_t)GG * NN * 4);         // cursor
        s += padded((size_t)GG * NE * 8);         // packed edges
        s += padded((size_t)GG * NN * DD * 4);    // h (compact rows)
        s += padded((size_t)NB_ * NG * NL * DD * 4); // sel
        s += padded((size_t)NB_ * NG * DD * 4);      // xsum
        s += padded((size_t)GG * NN * 4);         // candbm
        s += padded((size_t)GG * NN * 4);         // mark
        s += padded((size_t)GG * 64 * 4);         // partc
        s += padded((size_t)GG * NN * 4);         // list
        s += padded((size_t)GG * NN * 4);         // rank
        s += padded((size_t)GG * 64 * 4);         // nlist
        return s;
    };
    const int GG = (ws_size >= need(4)) ? 4 : 1;

    char* p = (char*)d_ws;
    auto alloc = [&](size_t b) -> void* { void* r = (void*)p; p += padded(b); return r; };
    int*   cnt  = (int*)  alloc((size_t)GG * (NN + 1) * 4);
    int*   part = (int*)  alloc((size_t)GG * 64 * 4);
    int*   roff = (int*)  alloc((size_t)GG * (NN + 1) * 4);
    int*   cur  = (int*)  alloc((size_t)GG * NN * 4);
    int2*  edg  = (int2*) alloc((size_t)GG * NE * 8);
    float* hb   = (float*)alloc((size_t)GG * NN * DD * 4);
    float* sel  = (float*)alloc((size_t)NB_ * NG * NL * DD * 4);
    float* xsum = (float*)alloc((size_t)NB_ * NG * DD * 4);
    int*   cbm  = (int*)  alloc((size_t)GG * NN * 4);
    int*   mark = (int*)  alloc((size_t)GG * NN * 4);
    int*   prtc = (int*)  alloc((size_t)GG * 64 * 4);
    int*   list = (int*)  alloc((size_t)GG * NN * 4);
    int*   rank = (int*)  alloc((size_t)GG * NN * 4);
    int*   nlst = (int*)  alloc((size_t)GG * 64 * 4);

    const int QB = (NE / 4 + 255) / 256;  // 4-edge-per-thread blocks
    const int CB = (NB_ * NL + 255) / 256;
    for (int g0 = 0; g0 < NG; g0 += GG) {
        hipMemsetAsync(cnt, 0, (size_t)GG * (NN + 1) * 4, stream);
        hipMemsetAsync(cbm, 0, (size_t)GG * NN * 4, stream);
        hipMemsetAsync(mark, 0, (size_t)GG * NN * 4, stream);
        k_candmark<<<dim3(CB, GG), 256, 0, stream>>>(cand, cbm, mark, g0);
        k_mark2   <<<dim3(QB, GG), 256, 0, stream>>>(src, dst, cbm, mark, cnt, g0);
        k_cscan1  <<<dim3(SCAN_NB, GG), 256, 0, stream>>>(mark, prtc);
        k_cscan3  <<<dim3(SCAN_NB, GG), 256, 0, stream>>>(mark, prtc, list, rank, nlst);
        k_scan1   <<<dim3(SCAN_NB, GG), 256, 0, stream>>>(cnt, part);
        k_scan3   <<<dim3(SCAN_NB, GG), 256, 0, stream>>>(cnt, part, roff, cur);
        k_scatter2<<<dim3(QB, GG), 256, 0, stream>>>(src, dst, ew, cbm, cur, edg, g0);
        k_conv_full<<<dim3(1792, GG), 256, 0, stream>>>(emb, roff, edg, Ws1, Wn1, b1, hb, list, nlst, g0);
        k_conv_cand<<<dim3((NB_ * NL) / 4, GG), 256, 0, stream>>>(hb, roff, edg, rank, Ws2, Wn2, b2, cand, sel, g0);
    }
    k_attn1<<<NB_ * NG, 256, 0, stream>>>(sel, Q1, K1, V1, xsum);
    k_attn2<<<NB_, 64, 0, stream>>>(xsum, Q2, K2, V2, out);
}